// Round 6
// baseline (350.792 us; speedup 1.0000x reference)
//
#include <hip/hip_runtime.h>

#define NB 64
#define NT 512
#define NVAR 16
#define VDIM 16
#define DD 64
#define FF 256
#define BT (NB*NT)
#define LN_EPS 1e-3f
#define LOG2E 1.4426950408889634f

typedef __attribute__((ext_vector_type(8))) short bf8;   // 8 bf16 = one MFMA A/B operand
typedef __attribute__((ext_vector_type(4))) float f4;
typedef __attribute__((ext_vector_type(4))) int i4;
typedef __attribute__((ext_vector_type(4))) unsigned u4;

// ---- ws layout (bytes) ----
#define CPROJ_OFF   0                        // 64*16*64 f32 = 256KB  (cproj + bt folded in)
#define RBIAS_OFF   262144                   // 64*16*64 f32 = 256KB  (bp - cproj@Wp)
#define WTP_OFF     524288                   // 16 vars x 4 frags x 64 x 16B = 64KB
#define BIGP_OFF    (524288+65536)           // 16 vars x 4 mats x 16 frags x 64 x 16B = 1MB
#define WSP_OFF     (524288+65536+1048576)   // 16 frags x 64 x 16B = 16KB
#define BGS_OFF     (524288+65536+1048576+16384) // bg*log2e, 16*64 f32 = 4KB
// mats: 0=Wp 1=W1 2=W2 3=Wg(prescaled by log2e)
// bigp frag layout per var-mat (16 frags): idx = (c*2+hl)*4 + Mi
//   c = 32-wide k-chunk (0/1), hl = 0:Wh 1:Wl, Mi = 16-wide m-chunk.
//   lane L holds W[k = 32c + 4(L>>4)+j (j=0..3) and 32c+16+4(L>>4)+j (j=4..7)][m=16Mi+(L&15)]

// ---- precise RNE split (prep-time only) ----
__device__ __forceinline__ void split1(float x, unsigned &hb, float &lo) {
    unsigned u = __builtin_bit_cast(unsigned, x);
    unsigned r = u + 0x7fffu + ((u >> 16) & 1u);
    hb = r >> 16;
    lo = x - __builtin_bit_cast(float, r & 0xffff0000u);
}
__device__ __forceinline__ unsigned rnepk(float x, float y) {
    unsigned a = __builtin_bit_cast(unsigned, x);
    unsigned b = __builtin_bit_cast(unsigned, y);
    a = a + 0x7fffu + ((a >> 16) & 1u);
    b = b + 0x7fffu + ((b >> 16) & 1u);
    return (a >> 16) | (b & 0xffff0000u);
}
__device__ __forceinline__ void split4(f4 v, unsigned &h0, unsigned &h1,
                                       unsigned &l0, unsigned &l1) {
    unsigned b0,b1,b2,b3; float q0,q1,q2,q3;
    split1(v.x,b0,q0); split1(v.y,b1,q1); split1(v.z,b2,q2); split1(v.w,b3,q3);
    h0 = b0 | (b1<<16); h1 = b2 | (b3<<16);
    l0 = rnepk(q0,q1); l1 = rnepk(q2,q3);
}
// ---- fast truncation split (hot path): hi = trunc(x), lo = trunc(x - hi) ----
__device__ __forceinline__ void split4f(f4 v, unsigned &h0, unsigned &h1,
                                        unsigned &l0, unsigned &l1) {
    unsigned a0 = __builtin_bit_cast(unsigned, v.x);
    unsigned a1 = __builtin_bit_cast(unsigned, v.y);
    unsigned a2 = __builtin_bit_cast(unsigned, v.z);
    unsigned a3 = __builtin_bit_cast(unsigned, v.w);
    unsigned m0 = a0 & 0xffff0000u, m1 = a1 & 0xffff0000u;
    unsigned m2 = a2 & 0xffff0000u, m3 = a3 & 0xffff0000u;
    h0 = (a0 >> 16) | m1;
    h1 = (a2 >> 16) | m3;
    float lx = v.x - __builtin_bit_cast(float, m0);
    float ly = v.y - __builtin_bit_cast(float, m1);
    float lz = v.z - __builtin_bit_cast(float, m2);
    float lw = v.w - __builtin_bit_cast(float, m3);
    l0 = (__builtin_bit_cast(unsigned, lx) >> 16) |
         (__builtin_bit_cast(unsigned, ly) & 0xffff0000u);
    l1 = (__builtin_bit_cast(unsigned, lz) >> 16) |
         (__builtin_bit_cast(unsigned, lw) & 0xffff0000u);
}
__device__ __forceinline__ bf8 afrag(u4 w) { return __builtin_bit_cast(bf8, w); }
__device__ __forceinline__ bf8 mk_b4(unsigned w0, unsigned w1, unsigned w2, unsigned w3) {
    i4 t; t.x = (int)w0; t.y = (int)w1; t.z = (int)w2; t.w = (int)w3;
    return __builtin_bit_cast(bf8, t);
}
// legacy duplicated-B operands (Wt stage, K=16 only)
__device__ __forceinline__ bf8 mk_bhh(unsigned h0, unsigned h1) {
    i4 t; t.x = (int)h0; t.y = (int)h1; t.z = (int)h0; t.w = (int)h1;
    return __builtin_bit_cast(bf8, t);
}
__device__ __forceinline__ bf8 mk_bl0(unsigned l0, unsigned l1) {
    i4 t; t.x = (int)l0; t.y = (int)l1; t.z = 0; t.w = 0;
    return __builtin_bit_cast(bf8, t);
}
__device__ __forceinline__ float bflo(unsigned w){ return __builtin_bit_cast(float, w<<16); }
__device__ __forceinline__ float bfhi(unsigned w){ return __builtin_bit_cast(float, w & 0xffff0000u); }

__device__ __forceinline__ f4 mfma2(f4 acc, bf8 Af, bf8 Bh, bf8 Bl) {
    acc = __builtin_amdgcn_mfma_f32_16x16x32_bf16(Af, Bh, acc, 0,0,0);
    acc = __builtin_amdgcn_mfma_f32_16x16x32_bf16(Af, Bl, acc, 0,0,0);
    return acc;
}

// acc (C-layout) -> B-operand frags of the next stage (pure in-lane repack)
__device__ __forceinline__ void acc_to_frags1(const f4 acc[4],
        unsigned fh[4][2], unsigned fl[4][2]) {
    #pragma unroll
    for (int Ks = 0; Ks < 4; ++Ks)
        split4f(acc[Ks], fh[Ks][0], fh[Ks][1], fl[Ks][0], fl[Ks][1]);
}
// One 64x64 GEMM-stage, full-K scheme: 6 MFMAs per Mi (was 8).
// Terms kept: Wh.xh (exact), Wl.xh, Wh.xl; dropped: Wl.xl (~2^-16) — same as before.
__device__ __forceinline__ void run_stage6(const u4* __restrict__ ap, int lane,
        const unsigned fh[4][2], const unsigned fl[4][2], f4 acc[4]) {
    const bf8 Bh0 = mk_b4(fh[0][0], fh[0][1], fh[1][0], fh[1][1]);  // xh, k 0..31
    const bf8 Bh1 = mk_b4(fh[2][0], fh[2][1], fh[3][0], fh[3][1]);  // xh, k 32..63
    const bf8 Bl0 = mk_b4(fl[0][0], fl[0][1], fl[1][0], fl[1][1]);  // xl, k 0..31
    const bf8 Bl1 = mk_b4(fl[2][0], fl[2][1], fl[3][0], fl[3][1]);  // xl, k 32..63
    #pragma unroll
    for (int Mi = 0; Mi < 4; ++Mi) {
        const u4 ah0 = ap[(     Mi)*64 + lane];
        const u4 al0 = ap[( 4 + Mi)*64 + lane];
        const u4 ah1 = ap[( 8 + Mi)*64 + lane];
        const u4 al1 = ap[(12 + Mi)*64 + lane];
        f4 a = acc[Mi];
        a = __builtin_amdgcn_mfma_f32_16x16x32_bf16(afrag(ah0), Bh0, a, 0,0,0);
        a = __builtin_amdgcn_mfma_f32_16x16x32_bf16(afrag(ah1), Bh1, a, 0,0,0);
        a = __builtin_amdgcn_mfma_f32_16x16x32_bf16(afrag(al0), Bh0, a, 0,0,0);
        a = __builtin_amdgcn_mfma_f32_16x16x32_bf16(afrag(al1), Bh1, a, 0,0,0);
        a = __builtin_amdgcn_mfma_f32_16x16x32_bf16(afrag(ah0), Bl0, a, 0,0,0);
        a = __builtin_amdgcn_mfma_f32_16x16x32_bf16(afrag(ah1), Bl1, a, 0,0,0);
        acc[Mi] = a;
    }
}
// Paired stage for (Wp, W1): both consume the SAME B operands (a-frags).
// Packs B once; per-Mi A loads keep transient register pressure flat while
// giving two independent 4-acc MFMA chains to interleave.
__device__ __forceinline__ void run_stage6_pair(const u4* __restrict__ ap0,
        const u4* __restrict__ ap1, int lane,
        const unsigned fh[4][2], const unsigned fl[4][2], f4 acc0[4], f4 acc1[4]) {
    const bf8 Bh0 = mk_b4(fh[0][0], fh[0][1], fh[1][0], fh[1][1]);
    const bf8 Bh1 = mk_b4(fh[2][0], fh[2][1], fh[3][0], fh[3][1]);
    const bf8 Bl0 = mk_b4(fl[0][0], fl[0][1], fl[1][0], fl[1][1]);
    const bf8 Bl1 = mk_b4(fl[2][0], fl[2][1], fl[3][0], fl[3][1]);
    #pragma unroll
    for (int Mi = 0; Mi < 4; ++Mi) {
        {
            const u4 ah0 = ap0[(     Mi)*64 + lane];
            const u4 al0 = ap0[( 4 + Mi)*64 + lane];
            const u4 ah1 = ap0[( 8 + Mi)*64 + lane];
            const u4 al1 = ap0[(12 + Mi)*64 + lane];
            f4 a = acc0[Mi];
            a = __builtin_amdgcn_mfma_f32_16x16x32_bf16(afrag(ah0), Bh0, a, 0,0,0);
            a = __builtin_amdgcn_mfma_f32_16x16x32_bf16(afrag(ah1), Bh1, a, 0,0,0);
            a = __builtin_amdgcn_mfma_f32_16x16x32_bf16(afrag(al0), Bh0, a, 0,0,0);
            a = __builtin_amdgcn_mfma_f32_16x16x32_bf16(afrag(al1), Bh1, a, 0,0,0);
            a = __builtin_amdgcn_mfma_f32_16x16x32_bf16(afrag(ah0), Bl0, a, 0,0,0);
            a = __builtin_amdgcn_mfma_f32_16x16x32_bf16(afrag(ah1), Bl1, a, 0,0,0);
            acc0[Mi] = a;
        }
        {
            const u4 ah0 = ap1[(     Mi)*64 + lane];
            const u4 al0 = ap1[( 4 + Mi)*64 + lane];
            const u4 ah1 = ap1[( 8 + Mi)*64 + lane];
            const u4 al1 = ap1[(12 + Mi)*64 + lane];
            f4 a = acc1[Mi];
            a = __builtin_amdgcn_mfma_f32_16x16x32_bf16(afrag(ah0), Bh0, a, 0,0,0);
            a = __builtin_amdgcn_mfma_f32_16x16x32_bf16(afrag(ah1), Bh1, a, 0,0,0);
            a = __builtin_amdgcn_mfma_f32_16x16x32_bf16(afrag(al0), Bh0, a, 0,0,0);
            a = __builtin_amdgcn_mfma_f32_16x16x32_bf16(afrag(al1), Bh1, a, 0,0,0);
            a = __builtin_amdgcn_mfma_f32_16x16x32_bf16(afrag(ah0), Bl0, a, 0,0,0);
            a = __builtin_amdgcn_mfma_f32_16x16x32_bf16(afrag(ah1), Bl1, a, 0,0,0);
            acc1[Mi] = a;
        }
    }
}

// Prep: weight pack (blocks 0..149) + cproj/rbias (blocks 150..405).
__global__ void prep_kernel(const float* __restrict__ Wt, const float* __restrict__ W1,
                            const float* __restrict__ W2, const float* __restrict__ Wg,
                            const float* __restrict__ Wp, const float* __restrict__ Ws,
                            const float* __restrict__ ctx, const float* __restrict__ Wctx,
                            const float* __restrict__ bp, const float* __restrict__ bg,
                            const float* __restrict__ bt,
                            u4* __restrict__ wtp, u4* __restrict__ bigp,
                            u4* __restrict__ wsp, float* __restrict__ cproj,
                            float* __restrict__ rbias, float* __restrict__ bgs) {
    if (blockIdx.x >= 150) {
        __shared__ float cp[4][64];
        const int sub = threadIdx.x >> 6, d = threadIdx.x & 63;
        const int bn = (blockIdx.x - 150) * 4 + sub;
        const int b = bn >> 4, n = bn & 15;
        const float* __restrict__ wc = Wctx + n * DD * DD;
        const float* __restrict__ c  = ctx + b * DD;
        float acc = 0.f;
        #pragma unroll 8
        for (int k = 0; k < DD; ++k) acc += c[k] * wc[k * DD + d];
        cproj[bn * DD + d] = acc + bt[n * DD + d];   // bt folded in for vsn
        cp[sub][d] = acc;                            // un-biased copy for rbias
        __syncthreads();
        const float* __restrict__ wp = Wp + n * DD * DD;
        float r = bp[n * DD + d];
        #pragma unroll 8
        for (int k = 0; k < DD; ++k) r -= cp[sub][k] * wp[k * DD + d];
        rbias[bn * DD + d] = r;
        return;
    }
    const int t = blockIdx.x * 256 + threadIdx.x;
    if (t < 32768) {
        // big mats: per thread one (var,mat,c,Mi) h-frag + l-frag (8 source floats)
        const int lane = t & 63, Mi = (t>>6)&3, c = (t>>8)&1, mat = (t>>9)&3, var = t>>11;
        const float* W = (mat==0) ? Wp : (mat==1) ? W1 : (mat==2) ? W2 : Wg;
        const float* src = W + var*4096;
        const int m = 16*Mi + (lane&15), q = lane>>4;
        const int k0 = 32*c + 4*q;
        const float sc = (mat == 3) ? LOG2E : 1.f;
        unsigned hb[8]; float lo[8];
        #pragma unroll
        for (int j = 0; j < 4; ++j) split1(sc*src[(k0+j)*64+m],    hb[j],   lo[j]);
        #pragma unroll
        for (int j = 0; j < 4; ++j) split1(sc*src[(k0+16+j)*64+m], hb[4+j], lo[4+j]);
        u4 hf, lf;
        hf.x = hb[0]|(hb[1]<<16); hf.y = hb[2]|(hb[3]<<16);
        hf.z = hb[4]|(hb[5]<<16); hf.w = hb[6]|(hb[7]<<16);
        lf.x = rnepk(lo[0],lo[1]); lf.y = rnepk(lo[2],lo[3]);
        lf.z = rnepk(lo[4],lo[5]); lf.w = rnepk(lo[6],lo[7]);
        u4* base = bigp + (size_t)((var*4+mat)*16)*64;
        base[((c*2+0)*4 + Mi)*64 + lane] = hf;
        base[((c*2+1)*4 + Mi)*64 + lane] = lf;
    } else if (t < 36864) {
        // Wt: legacy [Wh|Wl] frag (K=16 stage keeps duplicated-B mfma2)
        const int r = t - 32768;
        const int lane = r & 63, Mi = (r>>6)&3, var = r>>8;
        const int m = 16*Mi + (lane&15), k0 = 4*(lane>>4);
        const float* src = Wt + var*1024;
        f4 v;
        v.x = src[(k0+0)*64+m]; v.y = src[(k0+1)*64+m];
        v.z = src[(k0+2)*64+m]; v.w = src[(k0+3)*64+m];
        unsigned h0,h1,l0,l1; split4(v,h0,h1,l0,l1);
        u4 o; o.x=h0; o.y=h1; o.z=l0; o.w=l1;
        wtp[(var*4+Mi)*64 + lane] = o;
    } else if (t < 37376) {
        // Ws: full-K chunks (c=0..7), h-frag + l-frag per thread
        const int r = t - 36864;
        const int lane = r & 63, c = r >> 6;
        const int n = lane & 15, q = lane >> 4;
        const int k0 = 32*c + 4*q;
        unsigned hb[8]; float lo[8];
        #pragma unroll
        for (int j = 0; j < 4; ++j) split1(Ws[(k0+j)*16+n],    hb[j],   lo[j]);
        #pragma unroll
        for (int j = 0; j < 4; ++j) split1(Ws[(k0+16+j)*16+n], hb[4+j], lo[4+j]);
        u4 hf, lf;
        hf.x = hb[0]|(hb[1]<<16); hf.y = hb[2]|(hb[3]<<16);
        hf.z = hb[4]|(hb[5]<<16); hf.w = hb[6]|(hb[7]<<16);
        lf.x = rnepk(lo[0],lo[1]); lf.y = rnepk(lo[2],lo[3]);
        lf.z = rnepk(lo[4],lo[5]); lf.w = rnepk(lo[6],lo[7]);
        wsp[(c*2+0)*64 + lane] = hf;
        wsp[(c*2+1)*64 + lane] = lf;
    } else if (t < 38400) {
        const int r = t - 37376;
        bgs[r] = bg[r] * LOG2E;
    }
}

// Main: block = 512 threads = 8 waves, 64 tokens; grid = 512 (R0 skeleton).
// REGISTER-CAP LEDGER (hard-won):
//   cap 128 (R0: lb(512,4))  -> 64 arch VGPR, no spills, vsn 143.6us.
//   cap  96 (R4: lb(256,5))  -> 48 arch VGPR, 757MB scratch WRITE, 336us.
//   cap  64 (R1: lb(512,8))  -> 32 arch VGPR, 493MB scratch WRITE, 296us.
// => 4 waves/SIMD is the occupancy ceiling; never cap below 128.
// R5 LESSON: cutting MFMA/VALU work in 16-token blocks EXPOSED weight-load
// latency (stall time 40->86us): the removed VALU was the latency cover, and
// 16-token blocks doubled per-wave fixed overhead (4x logits redundancy) and
// 5.3x'd LDS bank conflicts (sel-in-LDS RMW). This round: R0's 64-token/8-var
// structure (proven latency hiding, 2x logits redundancy, register sel)
// + R5-verified full-K 6-MFMA stages + (Wp,W1) pairing + cprojb fold.
#define PSEL_OFF 0          // 128 rows (grp*64+tq*16+l15) x 68 dw = 8704 dw
#define WSEL_OFF 8704       // 4 tq x 16 n x 17 = 1088 dw
#define SMEM_DW  9792       // 39168 B; 2 blocks/CU = 78KB <= 160KB

__global__ __launch_bounds__(512, 4)
void vsn_kernel(const float* __restrict__ inp,
                const u4* __restrict__ wtp, const u4* __restrict__ bigp,
                const u4* __restrict__ wsp,
                const float* __restrict__ b1,
                const float* __restrict__ b2, const float* __restrict__ bgs,
                const float* __restrict__ rbias,
                const float* __restrict__ gamma_, const float* __restrict__ beta_,
                const float* __restrict__ bs,
                const float* __restrict__ cprojb,
                float* __restrict__ out_sel, float* __restrict__ out_w) {
    __shared__ float smem[SMEM_DW];

    const int tid  = threadIdx.x;
    const int lane = tid & 63;
    const int wv   = tid >> 6;
    const int grp  = wv & 1;                    // var group (8 vars)
    const int tq   = wv >> 1;                   // token quarter (16 tokens)
    const int qd   = lane >> 4;
    const int l15  = lane & 15;
    const int tile0 = blockIdx.x * 64;
    const int b     = blockIdx.x >> 3;          // tile0 / NT
    const int tok0  = tile0 + tq * 16;

    const float* row = inp + (size_t)(tok0 + l15) * FF;   // my token's feature row

    // ---------------- logits via MFMA + softmax (per wave, 16 tokens) -------
    {
        f4 lacc = *(const f4*)(bs + 4*qd);      // n = 4*qd + reg
        #pragma unroll 4
        for (int c = 0; c < 8; ++c) {
            const u4 wh = wsp[(c*2+0)*64 + lane];
            const u4 wl = wsp[(c*2+1)*64 + lane];
            const f4 v1 = *(const f4*)(row + 32*c + 4*qd);
            const f4 v2 = *(const f4*)(row + 32*c + 16 + 4*qd);
            unsigned h0,h1,l0,l1,h2,h3,l2,l3;
            split4f(v1,h0,h1,l0,l1);
            split4f(v2,h2,h3,l2,l3);
            const bf8 Bh = mk_b4(h0,h1,h2,h3);
            const bf8 Bl = mk_b4(l0,l1,l2,l3);
            lacc = __builtin_amdgcn_mfma_f32_16x16x32_bf16(afrag(wh), Bh, lacc, 0,0,0);
            lacc = __builtin_amdgcn_mfma_f32_16x16x32_bf16(afrag(wl), Bh, lacc, 0,0,0);
            lacc = __builtin_amdgcn_mfma_f32_16x16x32_bf16(afrag(wh), Bl, lacc, 0,0,0);
        }
        float mx = fmaxf(fmaxf(lacc.x,lacc.y), fmaxf(lacc.z,lacc.w));
        mx = fmaxf(mx, __shfl_xor(mx, 16));
        mx = fmaxf(mx, __shfl_xor(mx, 32));
        float e0 = __expf(lacc.x-mx), e1 = __expf(lacc.y-mx);
        float e2 = __expf(lacc.z-mx), e3 = __expf(lacc.w-mx);
        float s = e0+e1+e2+e3;
        s += __shfl_xor(s, 16);
        s += __shfl_xor(s, 32);
        const float rs = __builtin_amdgcn_rcpf(s);
        e0 *= rs; e1 *= rs; e2 *= rs; e3 *= rs;
        // both grp waves of a tq write identical bits -> benign duplicate;
        // each wave reads only rows its own lanes wrote -> no barrier.
        const int base = WSEL_OFF + tq*272 + (4*qd)*17 + l15;
        smem[base + 0*17] = e0;
        smem[base + 1*17] = e1;
        smem[base + 2*17] = e2;
        smem[base + 3*17] = e3;
        if (grp == 0) {
            f4 o; o.x=e0; o.y=e1; o.z=e2; o.w=e3;
            *(f4*)(out_w + (size_t)(tok0 + l15)*16 + 4*qd) = o;
        }
    }

    // ---------------- per-variable GRN chain (8 vars per wave) --------------
    f4 sel[4];
    #pragma unroll
    for (int Mi = 0; Mi < 4; ++Mi) sel[Mi] = (f4)0.f;

    #pragma unroll 1
    for (int vi = 0; vi < 8; ++vi) {
        const int n = grp*8 + vi;
        unsigned fh[4][2], fl[4][2];

        // a = Wt^T @ xv + (bt + cproj)  [bt folded into cprojb at prep time]
        f4 tacc[4];
        #pragma unroll
        for (int Mi = 0; Mi < 4; ++Mi)
            tacc[Mi] = *(const f4*)(cprojb + (size_t)(b*NVAR+n)*DD + 16*Mi + 4*qd);
        {
            const f4 v = *(const f4*)(row + n*16 + 4*qd);
            unsigned xh0,xh1,xl0,xl1;
            split4f(v, xh0, xh1, xl0, xl1);
            const bf8 Bh = mk_bhh(xh0, xh1);
            const bf8 Bl = mk_bl0(xl0, xl1);
            #pragma unroll
            for (int Mi = 0; Mi < 4; ++Mi) {
                const u4 w = wtp[(n*4+Mi)*64 + lane];
                tacc[Mi] = mfma2(tacc[Mi], afrag(w), Bh, Bl);
            }
        }
        acc_to_frags1(tacc, fh, fl);   // a-frags

        // res = Wp^T @ a + rbias; h1pre = W1^T @ a + b1  (shared B operands)
        f4 racc[4], hacc[4];
        #pragma unroll
        for (int Mi = 0; Mi < 4; ++Mi) {
            racc[Mi] = *(const f4*)(rbias + (size_t)(b*NVAR+n)*DD + 16*Mi + 4*qd);
            hacc[Mi] = *(const f4*)(b1 + n*DD + 16*Mi + 4*qd);
        }
        run_stage6_pair(bigp + (size_t)(n*4 + 0)*1024,
                        bigp + (size_t)(n*4 + 1)*1024, lane, fh, fl, racc, hacc);
        #pragma unroll
        for (int Mi = 0; Mi < 4; ++Mi) {
            f4& v = hacc[Mi];
            v.x = v.x > 0.f ? v.x : (__expf(v.x)-1.f);
            v.y = v.y > 0.f ? v.y : (__expf(v.y)-1.f);
            v.z = v.z > 0.f ? v.z : (__expf(v.z)-1.f);
            v.w = v.w > 0.f ? v.w : (__expf(v.w)-1.f);
        }
        acc_to_frags1(hacc, fh, fl);   // h1 frags

        // h2 = W2^T @ h1 + b2
        #pragma unroll
        for (int Mi = 0; Mi < 4; ++Mi) hacc[Mi] = *(const f4*)(b2 + n*DD + 16*Mi + 4*qd);
        run_stage6(bigp + (size_t)(n*4 + 2)*1024, lane, fh, fl, hacc);
        acc_to_frags1(hacc, fh, fl);   // h2 frags (fp32 recon from hi+lo below)

        // gate logits (pre-scaled by log2e) = Wg'^T @ h2 + bgs
        f4 gacc[4];
        #pragma unroll
        for (int Mi = 0; Mi < 4; ++Mi) gacc[Mi] = *(const f4*)(bgs + n*DD + 16*Mi + 4*qd);
        run_stage6(bigp + (size_t)(n*4 + 3)*1024, lane, fh, fl, gacc);

        // z = h2 * rcp(1 + exp2(-g')) + res
        f4 z[4];
        #pragma unroll
        for (int Mi = 0; Mi < 4; ++Mi) {
            const float h2x = bflo(fh[Mi][0]) + bflo(fl[Mi][0]);
            const float h2y = bfhi(fh[Mi][0]) + bfhi(fl[Mi][0]);
            const float h2z = bflo(fh[Mi][1]) + bflo(fl[Mi][1]);
            const float h2w = bfhi(fh[Mi][1]) + bfhi(fl[Mi][1]);
            const f4 gv = gacc[Mi];
            z[Mi].x = h2x * __builtin_amdgcn_rcpf(1.f + __builtin_amdgcn_exp2f(-gv.x)) + racc[Mi].x;
            z[Mi].y = h2y * __builtin_amdgcn_rcpf(1.f + __builtin_amdgcn_exp2f(-gv.y)) + racc[Mi].y;
            z[Mi].z = h2z * __builtin_amdgcn_rcpf(1.f + __builtin_amdgcn_exp2f(-gv.z)) + racc[Mi].z;
            z[Mi].w = h2w * __builtin_amdgcn_rcpf(1.f + __builtin_amdgcn_exp2f(-gv.w)) + racc[Mi].w;
        }
        // LayerNorm over d (16 in-lane + cross-quad butterfly)
        float s = 0.f;
        #pragma unroll
        for (int Mi = 0; Mi < 4; ++Mi) s += z[Mi].x + z[Mi].y + z[Mi].z + z[Mi].w;
        s += __shfl_xor(s, 16);
        s += __shfl_xor(s, 32);
        const float mu = s * (1.f/64.f);
        float q = 0.f;
        #pragma unroll
        for (int Mi = 0; Mi < 4; ++Mi) {
            float dx = z[Mi].x - mu; q += dx*dx;
            dx = z[Mi].y - mu; q += dx*dx;
            dx = z[Mi].z - mu; q += dx*dx;
            dx = z[Mi].w - mu; q += dx*dx;
        }
        q += __shfl_xor(q, 16);
        q += __shfl_xor(q, 32);
        const float rstd = rsqrtf(q*(1.f/64.f) + LN_EPS);

        const float wn = smem[WSEL_OFF + tq*272 + n*17 + l15];
        #pragma unroll
        for (int Mi = 0; Mi < 4; ++Mi) {
            const f4 gm = *(const f4*)(gamma_ + n*DD + 16*Mi + 4*qd);
            const f4 bb = *(const f4*)(beta_  + n*DD + 16*Mi + 4*qd);
            sel[Mi].x += wn*((z[Mi].x-mu)*rstd*gm.x + bb.x);
            sel[Mi].y += wn*((z[Mi].y-mu)*rstd*gm.y + bb.y);
            sel[Mi].z += wn*((z[Mi].z-mu)*rstd*gm.z + bb.z);
            sel[Mi].w += wn*((z[Mi].w-mu)*rstd*gm.w + bb.w);
        }
    }

    // partial sel -> LDS row (grp*64 + tq*16 + l15), stride 68 dw (17x16B, aligned)
    {
        const int base = PSEL_OFF + (grp*64 + tq*16 + l15)*68;
        #pragma unroll
        for (int Mi = 0; Mi < 4; ++Mi)
            *(f4*)&smem[base + 16*Mi + 4*qd] = sel[Mi];
    }
    __syncthreads();
    {
        const int tokloc = tid >> 3;            // 0..63 (the 64 tokens of this tile)
        const int d0 = (tid & 7) * 8;
        const int rbase = PSEL_OFF + tokloc*68 + d0;
        const f4 a0 = *(f4*)&smem[rbase];
        const f4 a1 = *(f4*)&smem[rbase + 4];
        const f4 b0 = *(f4*)&smem[rbase + 64*68];
        const f4 b1v = *(f4*)&smem[rbase + 64*68 + 4];
        float* po = out_sel + (size_t)(tile0+tokloc)*DD + d0;
        *(f4*)po     = a0 + b0;
        *(f4*)(po+4) = a1 + b1v;
    }
}

extern "C" void kernel_launch(void* const* d_in, const int* in_sizes, int n_in,
                              void* d_out, int out_size, void* d_ws, size_t ws_size,
                              hipStream_t stream) {
    const float* inp  = (const float*)d_in[0];
    const float* ctx  = (const float*)d_in[1];
    const float* Wt   = (const float*)d_in[2];
    const float* bt   = (const float*)d_in[3];
    const float* Wctx = (const float*)d_in[4];
    const float* W1   = (const float*)d_in[5];
    const float* b1   = (const float*)d_in[6];
    const float* W2   = (const float*)d_in[7];
    const float* b2   = (const float*)d_in[8];
    const float* Wg   = (const float*)d_in[9];
    const float* bg   = (const float*)d_in[10];
    const float* Wp   = (const float*)d_in[11];
    const float* bp   = (const float*)d_in[12];
    const float* gm   = (const float*)d_in[13];
    const float* bt2  = (const float*)d_in[14];
    const float* Ws   = (const float*)d_in[15];
    const float* bs   = (const float*)d_in[16];

    float* out_sel = (float*)d_out;
    float* out_w   = out_sel + (size_t)BT * DD;

    char* ws = (char*)d_ws;
    float* cproj = (float*)(ws + CPROJ_OFF);
    float* rbias = (float*)(ws + RBIAS_OFF);
    u4* wtp  = (u4*)(ws + WTP_OFF);
    u4* bigp = (u4*)(ws + BIGP_OFF);
    u4* wsp  = (u4*)(ws + WSP_OFF);
    float* bgs = (float*)(ws + BGS_OFF);

    prep_kernel<<<406, 256, 0, stream>>>(Wt, W1, W2, Wg, Wp, Ws, ctx, Wctx, bp, bg, bt,
                                         wtp, bigp, wsp, cproj, rbias, bgs);
    vsn_kernel<<<BT / 64, 512, 0, stream>>>(inp, wtp, bigp, wsp,
                                            b1, b2, bgs, rbias, gm, bt2, bs,
                                            cproj, out_sel, out_w);
}

// Round 7
// 228.289 us; speedup vs baseline: 1.5366x; 1.5366x over previous
//
#include <hip/hip_runtime.h>

#define NB 64
#define NT 512
#define NVAR 16
#define VDIM 16
#define DD 64
#define FF 256
#define BT (NB*NT)
#define LN_EPS 1e-3f
#define LOG2E 1.4426950408889634f

typedef __attribute__((ext_vector_type(8))) short bf8;   // 8 bf16 = one MFMA A/B operand
typedef __attribute__((ext_vector_type(4))) float f4;
typedef __attribute__((ext_vector_type(4))) int i4;
typedef __attribute__((ext_vector_type(4))) unsigned u4;

// ---- ws layout (bytes) ----
#define CPROJ_OFF   0                        // 64*16*64 f32 = 256KB  (cproj + bt folded in)
#define RBIAS_OFF   262144                   // 64*16*64 f32 = 256KB  (bp - cproj@Wp)
#define WTP_OFF     524288                   // 16 vars x 4 frags x 64 x 16B = 64KB
#define BIGP_OFF    (524288+65536)           // 16 vars x 4 mats x 16 frags x 64 x 16B = 1MB
#define WSP_OFF     (524288+65536+1048576)   // 16 frags x 64 x 16B = 16KB
#define BGS_OFF     (524288+65536+1048576+16384) // bg*log2e, 16*64 f32 = 4KB
// mats: 0=Wp 1=W1 2=W2 3=Wg(prescaled by log2e)
// bigp frag layout per var-mat (16 frags): idx = (c*2+hl)*4 + Mi
//   c = 32-wide k-chunk (0/1), hl = 0:Wh 1:Wl, Mi = 16-wide m-chunk.
//   lane L holds W[k = 32c + 4(L>>4)+j (j=0..3) and 32c+16+4(L>>4)+j (j=4..7)][m=16Mi+(L&15)]

// ---- precise RNE split (prep-time only) ----
__device__ __forceinline__ void split1(float x, unsigned &hb, float &lo) {
    unsigned u = __builtin_bit_cast(unsigned, x);
    unsigned r = u + 0x7fffu + ((u >> 16) & 1u);
    hb = r >> 16;
    lo = x - __builtin_bit_cast(float, r & 0xffff0000u);
}
__device__ __forceinline__ unsigned rnepk(float x, float y) {
    unsigned a = __builtin_bit_cast(unsigned, x);
    unsigned b = __builtin_bit_cast(unsigned, y);
    a = a + 0x7fffu + ((a >> 16) & 1u);
    b = b + 0x7fffu + ((b >> 16) & 1u);
    return (a >> 16) | (b & 0xffff0000u);
}
__device__ __forceinline__ void split4(f4 v, unsigned &h0, unsigned &h1,
                                       unsigned &l0, unsigned &l1) {
    unsigned b0,b1,b2,b3; float q0,q1,q2,q3;
    split1(v.x,b0,q0); split1(v.y,b1,q1); split1(v.z,b2,q2); split1(v.w,b3,q3);
    h0 = b0 | (b1<<16); h1 = b2 | (b3<<16);
    l0 = rnepk(q0,q1); l1 = rnepk(q2,q3);
}
// ---- fast truncation split (hot path): hi = trunc(x), lo = trunc(x - hi) ----
__device__ __forceinline__ void split4f(f4 v, unsigned &h0, unsigned &h1,
                                        unsigned &l0, unsigned &l1) {
    unsigned a0 = __builtin_bit_cast(unsigned, v.x);
    unsigned a1 = __builtin_bit_cast(unsigned, v.y);
    unsigned a2 = __builtin_bit_cast(unsigned, v.z);
    unsigned a3 = __builtin_bit_cast(unsigned, v.w);
    unsigned m0 = a0 & 0xffff0000u, m1 = a1 & 0xffff0000u;
    unsigned m2 = a2 & 0xffff0000u, m3 = a3 & 0xffff0000u;
    h0 = (a0 >> 16) | m1;
    h1 = (a2 >> 16) | m3;
    float lx = v.x - __builtin_bit_cast(float, m0);
    float ly = v.y - __builtin_bit_cast(float, m1);
    float lz = v.z - __builtin_bit_cast(float, m2);
    float lw = v.w - __builtin_bit_cast(float, m3);
    l0 = (__builtin_bit_cast(unsigned, lx) >> 16) |
         (__builtin_bit_cast(unsigned, ly) & 0xffff0000u);
    l1 = (__builtin_bit_cast(unsigned, lz) >> 16) |
         (__builtin_bit_cast(unsigned, lw) & 0xffff0000u);
}
__device__ __forceinline__ bf8 afrag(u4 w) { return __builtin_bit_cast(bf8, w); }
__device__ __forceinline__ bf8 mk_b4(unsigned w0, unsigned w1, unsigned w2, unsigned w3) {
    i4 t; t.x = (int)w0; t.y = (int)w1; t.z = (int)w2; t.w = (int)w3;
    return __builtin_bit_cast(bf8, t);
}
// legacy duplicated-B operands (Wt stage, K=16 only)
__device__ __forceinline__ bf8 mk_bhh(unsigned h0, unsigned h1) {
    i4 t; t.x = (int)h0; t.y = (int)h1; t.z = (int)h0; t.w = (int)h1;
    return __builtin_bit_cast(bf8, t);
}
__device__ __forceinline__ bf8 mk_bl0(unsigned l0, unsigned l1) {
    i4 t; t.x = (int)l0; t.y = (int)l1; t.z = 0; t.w = 0;
    return __builtin_bit_cast(bf8, t);
}
__device__ __forceinline__ float bflo(unsigned w){ return __builtin_bit_cast(float, w<<16); }
__device__ __forceinline__ float bfhi(unsigned w){ return __builtin_bit_cast(float, w & 0xffff0000u); }

__device__ __forceinline__ f4 mfma2(f4 acc, bf8 Af, bf8 Bh, bf8 Bl) {
    acc = __builtin_amdgcn_mfma_f32_16x16x32_bf16(Af, Bh, acc, 0,0,0);
    acc = __builtin_amdgcn_mfma_f32_16x16x32_bf16(Af, Bl, acc, 0,0,0);
    return acc;
}

// acc (C-layout) -> B-operand frags of the next stage (pure in-lane repack)
__device__ __forceinline__ void acc_to_frags1(const f4 acc[4],
        unsigned fh[4][2], unsigned fl[4][2]) {
    #pragma unroll
    for (int Ks = 0; Ks < 4; ++Ks)
        split4f(acc[Ks], fh[Ks][0], fh[Ks][1], fl[Ks][0], fl[Ks][1]);
}
// One 64x64 GEMM-stage, full-K scheme: 6 MFMAs per Mi (was 8).
// Terms kept: Wh.xh (exact), Wl.xh, Wh.xl; dropped: Wl.xl (~2^-16) — same as before.
__device__ __forceinline__ void run_stage6(const u4* __restrict__ ap, int lane,
        const unsigned fh[4][2], const unsigned fl[4][2], f4 acc[4]) {
    const bf8 Bh0 = mk_b4(fh[0][0], fh[0][1], fh[1][0], fh[1][1]);  // xh, k 0..31
    const bf8 Bh1 = mk_b4(fh[2][0], fh[2][1], fh[3][0], fh[3][1]);  // xh, k 32..63
    const bf8 Bl0 = mk_b4(fl[0][0], fl[0][1], fl[1][0], fl[1][1]);  // xl, k 0..31
    const bf8 Bl1 = mk_b4(fl[2][0], fl[2][1], fl[3][0], fl[3][1]);  // xl, k 32..63
    #pragma unroll
    for (int Mi = 0; Mi < 4; ++Mi) {
        const u4 ah0 = ap[(     Mi)*64 + lane];
        const u4 al0 = ap[( 4 + Mi)*64 + lane];
        const u4 ah1 = ap[( 8 + Mi)*64 + lane];
        const u4 al1 = ap[(12 + Mi)*64 + lane];
        f4 a = acc[Mi];
        a = __builtin_amdgcn_mfma_f32_16x16x32_bf16(afrag(ah0), Bh0, a, 0,0,0);
        a = __builtin_amdgcn_mfma_f32_16x16x32_bf16(afrag(ah1), Bh1, a, 0,0,0);
        a = __builtin_amdgcn_mfma_f32_16x16x32_bf16(afrag(al0), Bh0, a, 0,0,0);
        a = __builtin_amdgcn_mfma_f32_16x16x32_bf16(afrag(al1), Bh1, a, 0,0,0);
        a = __builtin_amdgcn_mfma_f32_16x16x32_bf16(afrag(ah0), Bl0, a, 0,0,0);
        a = __builtin_amdgcn_mfma_f32_16x16x32_bf16(afrag(ah1), Bl1, a, 0,0,0);
        acc[Mi] = a;
    }
}
// Paired stage for (Wp, W1): both consume the SAME B operands (a-frags).
// Packs B once; per-Mi A loads keep transient register pressure flat while
// giving two independent 4-acc MFMA chains to interleave.
__device__ __forceinline__ void run_stage6_pair(const u4* __restrict__ ap0,
        const u4* __restrict__ ap1, int lane,
        const unsigned fh[4][2], const unsigned fl[4][2], f4 acc0[4], f4 acc1[4]) {
    const bf8 Bh0 = mk_b4(fh[0][0], fh[0][1], fh[1][0], fh[1][1]);
    const bf8 Bh1 = mk_b4(fh[2][0], fh[2][1], fh[3][0], fh[3][1]);
    const bf8 Bl0 = mk_b4(fl[0][0], fl[0][1], fl[1][0], fl[1][1]);
    const bf8 Bl1 = mk_b4(fl[2][0], fl[2][1], fl[3][0], fl[3][1]);
    #pragma unroll
    for (int Mi = 0; Mi < 4; ++Mi) {
        {
            const u4 ah0 = ap0[(     Mi)*64 + lane];
            const u4 al0 = ap0[( 4 + Mi)*64 + lane];
            const u4 ah1 = ap0[( 8 + Mi)*64 + lane];
            const u4 al1 = ap0[(12 + Mi)*64 + lane];
            f4 a = acc0[Mi];
            a = __builtin_amdgcn_mfma_f32_16x16x32_bf16(afrag(ah0), Bh0, a, 0,0,0);
            a = __builtin_amdgcn_mfma_f32_16x16x32_bf16(afrag(ah1), Bh1, a, 0,0,0);
            a = __builtin_amdgcn_mfma_f32_16x16x32_bf16(afrag(al0), Bh0, a, 0,0,0);
            a = __builtin_amdgcn_mfma_f32_16x16x32_bf16(afrag(al1), Bh1, a, 0,0,0);
            a = __builtin_amdgcn_mfma_f32_16x16x32_bf16(afrag(ah0), Bl0, a, 0,0,0);
            a = __builtin_amdgcn_mfma_f32_16x16x32_bf16(afrag(ah1), Bl1, a, 0,0,0);
            acc0[Mi] = a;
        }
        {
            const u4 ah0 = ap1[(     Mi)*64 + lane];
            const u4 al0 = ap1[( 4 + Mi)*64 + lane];
            const u4 ah1 = ap1[( 8 + Mi)*64 + lane];
            const u4 al1 = ap1[(12 + Mi)*64 + lane];
            f4 a = acc1[Mi];
            a = __builtin_amdgcn_mfma_f32_16x16x32_bf16(afrag(ah0), Bh0, a, 0,0,0);
            a = __builtin_amdgcn_mfma_f32_16x16x32_bf16(afrag(ah1), Bh1, a, 0,0,0);
            a = __builtin_amdgcn_mfma_f32_16x16x32_bf16(afrag(al0), Bh0, a, 0,0,0);
            a = __builtin_amdgcn_mfma_f32_16x16x32_bf16(afrag(al1), Bh1, a, 0,0,0);
            a = __builtin_amdgcn_mfma_f32_16x16x32_bf16(afrag(ah0), Bl0, a, 0,0,0);
            a = __builtin_amdgcn_mfma_f32_16x16x32_bf16(afrag(ah1), Bl1, a, 0,0,0);
            acc1[Mi] = a;
        }
    }
}

// Prep: weight pack (blocks 0..149) + cproj/rbias (blocks 150..405).
__global__ void prep_kernel(const float* __restrict__ Wt, const float* __restrict__ W1,
                            const float* __restrict__ W2, const float* __restrict__ Wg,
                            const float* __restrict__ Wp, const float* __restrict__ Ws,
                            const float* __restrict__ ctx, const float* __restrict__ Wctx,
                            const float* __restrict__ bp, const float* __restrict__ bg,
                            const float* __restrict__ bt,
                            u4* __restrict__ wtp, u4* __restrict__ bigp,
                            u4* __restrict__ wsp, float* __restrict__ cproj,
                            float* __restrict__ rbias, float* __restrict__ bgs) {
    if (blockIdx.x >= 150) {
        __shared__ float cp[4][64];
        const int sub = threadIdx.x >> 6, d = threadIdx.x & 63;
        const int bn = (blockIdx.x - 150) * 4 + sub;
        const int b = bn >> 4, n = bn & 15;
        const float* __restrict__ wc = Wctx + n * DD * DD;
        const float* __restrict__ c  = ctx + b * DD;
        float acc = 0.f;
        #pragma unroll 8
        for (int k = 0; k < DD; ++k) acc += c[k] * wc[k * DD + d];
        cproj[bn * DD + d] = acc + bt[n * DD + d];   // bt folded in for vsn
        cp[sub][d] = acc;                            // un-biased copy for rbias
        __syncthreads();
        const float* __restrict__ wp = Wp + n * DD * DD;
        float r = bp[n * DD + d];
        #pragma unroll 8
        for (int k = 0; k < DD; ++k) r -= cp[sub][k] * wp[k * DD + d];
        rbias[bn * DD + d] = r;
        return;
    }
    const int t = blockIdx.x * 256 + threadIdx.x;
    if (t < 32768) {
        // big mats: per thread one (var,mat,c,Mi) h-frag + l-frag (8 source floats)
        const int lane = t & 63, Mi = (t>>6)&3, c = (t>>8)&1, mat = (t>>9)&3, var = t>>11;
        const float* W = (mat==0) ? Wp : (mat==1) ? W1 : (mat==2) ? W2 : Wg;
        const float* src = W + var*4096;
        const int m = 16*Mi + (lane&15), q = lane>>4;
        const int k0 = 32*c + 4*q;
        const float sc = (mat == 3) ? LOG2E : 1.f;
        unsigned hb[8]; float lo[8];
        #pragma unroll
        for (int j = 0; j < 4; ++j) split1(sc*src[(k0+j)*64+m],    hb[j],   lo[j]);
        #pragma unroll
        for (int j = 0; j < 4; ++j) split1(sc*src[(k0+16+j)*64+m], hb[4+j], lo[4+j]);
        u4 hf, lf;
        hf.x = hb[0]|(hb[1]<<16); hf.y = hb[2]|(hb[3]<<16);
        hf.z = hb[4]|(hb[5]<<16); hf.w = hb[6]|(hb[7]<<16);
        lf.x = rnepk(lo[0],lo[1]); lf.y = rnepk(lo[2],lo[3]);
        lf.z = rnepk(lo[4],lo[5]); lf.w = rnepk(lo[6],lo[7]);
        u4* base = bigp + (size_t)((var*4+mat)*16)*64;
        base[((c*2+0)*4 + Mi)*64 + lane] = hf;
        base[((c*2+1)*4 + Mi)*64 + lane] = lf;
    } else if (t < 36864) {
        // Wt: legacy [Wh|Wl] frag (K=16 stage keeps duplicated-B mfma2)
        const int r = t - 32768;
        const int lane = r & 63, Mi = (r>>6)&3, var = r>>8;
        const int m = 16*Mi + (lane&15), k0 = 4*(lane>>4);
        const float* src = Wt + var*1024;
        f4 v;
        v.x = src[(k0+0)*64+m]; v.y = src[(k0+1)*64+m];
        v.z = src[(k0+2)*64+m]; v.w = src[(k0+3)*64+m];
        unsigned h0,h1,l0,l1; split4(v,h0,h1,l0,l1);
        u4 o; o.x=h0; o.y=h1; o.z=l0; o.w=l1;
        wtp[(var*4+Mi)*64 + lane] = o;
    } else if (t < 37376) {
        // Ws: full-K chunks (c=0..7), h-frag + l-frag per thread
        const int r = t - 36864;
        const int lane = r & 63, c = r >> 6;
        const int n = lane & 15, q = lane >> 4;
        const int k0 = 32*c + 4*q;
        unsigned hb[8]; float lo[8];
        #pragma unroll
        for (int j = 0; j < 4; ++j) split1(Ws[(k0+j)*16+n],    hb[j],   lo[j]);
        #pragma unroll
        for (int j = 0; j < 4; ++j) split1(Ws[(k0+16+j)*16+n], hb[4+j], lo[4+j]);
        u4 hf, lf;
        hf.x = hb[0]|(hb[1]<<16); hf.y = hb[2]|(hb[3]<<16);
        hf.z = hb[4]|(hb[5]<<16); hf.w = hb[6]|(hb[7]<<16);
        lf.x = rnepk(lo[0],lo[1]); lf.y = rnepk(lo[2],lo[3]);
        lf.z = rnepk(lo[4],lo[5]); lf.w = rnepk(lo[6],lo[7]);
        wsp[(c*2+0)*64 + lane] = hf;
        wsp[(c*2+1)*64 + lane] = lf;
    } else if (t < 38400) {
        const int r = t - 37376;
        bgs[r] = bg[r] * LOG2E;
    }
}

// Main: block = 512 threads = 8 waves, 64 tokens; grid = 512 (R0 skeleton).
// REGISTER-CAP LEDGER (hard-won):
//   cap 128, R0 body (8-MFMA, sel in regs)          -> fits, 143.6us.
//   cap 128, R5 body (pair+6-MFMA, sel in LDS)      -> fits, 150.5us (16-tok blocks).
//   cap 128, R6 body (pair+6-MFMA, sel in REGS)     -> SPILLS 503MB, 264us.
//   cap <128 (R1/R4)                                -> catastrophic spills.
// => the pair+6-MFMA body fits ONLY with sel in LDS (its wider transient
// A-load sets eat R0's slack). R5's per-block LDS-RMW conflict rate was modest
// (256/blk vs 192/blk) — sel-in-LDS is cheap; R5's real cost was 4x logits
// redundancy + 2x wave count of 16-token blocks.
// THIS ROUND: R0's 64-token/8-var skeleton + R5's exact spill-free body.
#define PSEL_OFF 0          // 128 rows (grp*64+tq*16+l15) x 68 dw = 8704 dw
#define WSEL_OFF 8704       // 4 tq x 16 n x 17 = 1088 dw
#define SMEM_DW  9792       // 39168 B; 2 blocks/CU = 78KB <= 160KB

__global__ __launch_bounds__(512, 4)
void vsn_kernel(const float* __restrict__ inp,
                const u4* __restrict__ wtp, const u4* __restrict__ bigp,
                const u4* __restrict__ wsp,
                const float* __restrict__ b1,
                const float* __restrict__ b2, const float* __restrict__ bgs,
                const float* __restrict__ rbias,
                const float* __restrict__ gamma_, const float* __restrict__ beta_,
                const float* __restrict__ bs,
                const float* __restrict__ cprojb,
                float* __restrict__ out_sel, float* __restrict__ out_w) {
    __shared__ float smem[SMEM_DW];

    const int tid  = threadIdx.x;
    const int lane = tid & 63;
    const int wv   = tid >> 6;
    const int grp  = wv & 1;                    // var group (8 vars)
    const int tq   = wv >> 1;                   // token quarter (16 tokens)
    const int qd   = lane >> 4;
    const int l15  = lane & 15;
    const int tile0 = blockIdx.x * 64;
    const int b     = blockIdx.x >> 3;          // tile0 / NT
    const int tok0  = tile0 + tq * 16;

    const float* row = inp + (size_t)(tok0 + l15) * FF;   // my token's feature row

    // ---------------- logits via MFMA + softmax (per wave, 16 tokens) -------
    {
        f4 lacc = *(const f4*)(bs + 4*qd);      // n = 4*qd + reg
        #pragma unroll 4
        for (int c = 0; c < 8; ++c) {
            const u4 wh = wsp[(c*2+0)*64 + lane];
            const u4 wl = wsp[(c*2+1)*64 + lane];
            const f4 v1 = *(const f4*)(row + 32*c + 4*qd);
            const f4 v2 = *(const f4*)(row + 32*c + 16 + 4*qd);
            unsigned h0,h1,l0,l1,h2,h3,l2,l3;
            split4f(v1,h0,h1,l0,l1);
            split4f(v2,h2,h3,l2,l3);
            const bf8 Bh = mk_b4(h0,h1,h2,h3);
            const bf8 Bl = mk_b4(l0,l1,l2,l3);
            lacc = __builtin_amdgcn_mfma_f32_16x16x32_bf16(afrag(wh), Bh, lacc, 0,0,0);
            lacc = __builtin_amdgcn_mfma_f32_16x16x32_bf16(afrag(wl), Bh, lacc, 0,0,0);
            lacc = __builtin_amdgcn_mfma_f32_16x16x32_bf16(afrag(wh), Bl, lacc, 0,0,0);
        }
        float mx = fmaxf(fmaxf(lacc.x,lacc.y), fmaxf(lacc.z,lacc.w));
        mx = fmaxf(mx, __shfl_xor(mx, 16));
        mx = fmaxf(mx, __shfl_xor(mx, 32));
        float e0 = __expf(lacc.x-mx), e1 = __expf(lacc.y-mx);
        float e2 = __expf(lacc.z-mx), e3 = __expf(lacc.w-mx);
        float s = e0+e1+e2+e3;
        s += __shfl_xor(s, 16);
        s += __shfl_xor(s, 32);
        const float rs = __builtin_amdgcn_rcpf(s);
        e0 *= rs; e1 *= rs; e2 *= rs; e3 *= rs;
        // both grp waves of a tq write identical bits -> benign duplicate;
        // each wave reads only rows its own lanes wrote -> no barrier.
        const int base = WSEL_OFF + tq*272 + (4*qd)*17 + l15;
        smem[base + 0*17] = e0;
        smem[base + 1*17] = e1;
        smem[base + 2*17] = e2;
        smem[base + 3*17] = e3;
        if (grp == 0) {
            f4 o; o.x=e0; o.y=e1; o.z=e2; o.w=e3;
            *(f4*)(out_w + (size_t)(tok0 + l15)*16 + 4*qd) = o;
        }
    }

    // ---------------- per-variable GRN chain (8 vars per wave) --------------
    // sel accumulates in LDS (lane-private row chunks; no races, no barrier):
    // this keeps the pair+6-MFMA body under the 128-reg cap (see ledger).
    const int sbase = PSEL_OFF + (grp*64 + tq*16 + l15)*68 + 4*qd;

    #pragma unroll 1
    for (int vi = 0; vi < 8; ++vi) {
        const int n = grp*8 + vi;
        unsigned fh[4][2], fl[4][2];

        // a = Wt^T @ xv + (bt + cproj)  [bt folded into cprojb at prep time]
        f4 tacc[4];
        #pragma unroll
        for (int Mi = 0; Mi < 4; ++Mi)
            tacc[Mi] = *(const f4*)(cprojb + (size_t)(b*NVAR+n)*DD + 16*Mi + 4*qd);
        {
            const f4 v = *(const f4*)(row + n*16 + 4*qd);
            unsigned xh0,xh1,xl0,xl1;
            split4f(v, xh0, xh1, xl0, xl1);
            const bf8 Bh = mk_bhh(xh0, xh1);
            const bf8 Bl = mk_bl0(xl0, xl1);
            #pragma unroll
            for (int Mi = 0; Mi < 4; ++Mi) {
                const u4 w = wtp[(n*4+Mi)*64 + lane];
                tacc[Mi] = mfma2(tacc[Mi], afrag(w), Bh, Bl);
            }
        }
        acc_to_frags1(tacc, fh, fl);   // a-frags

        // res = Wp^T @ a + rbias; h1pre = W1^T @ a + b1  (shared B operands)
        f4 racc[4], hacc[4];
        #pragma unroll
        for (int Mi = 0; Mi < 4; ++Mi) {
            racc[Mi] = *(const f4*)(rbias + (size_t)(b*NVAR+n)*DD + 16*Mi + 4*qd);
            hacc[Mi] = *(const f4*)(b1 + n*DD + 16*Mi + 4*qd);
        }
        run_stage6_pair(bigp + (size_t)(n*4 + 0)*1024,
                        bigp + (size_t)(n*4 + 1)*1024, lane, fh, fl, racc, hacc);
        #pragma unroll
        for (int Mi = 0; Mi < 4; ++Mi) {
            f4& v = hacc[Mi];
            v.x = v.x > 0.f ? v.x : (__expf(v.x)-1.f);
            v.y = v.y > 0.f ? v.y : (__expf(v.y)-1.f);
            v.z = v.z > 0.f ? v.z : (__expf(v.z)-1.f);
            v.w = v.w > 0.f ? v.w : (__expf(v.w)-1.f);
        }
        acc_to_frags1(hacc, fh, fl);   // h1 frags

        // h2 = W2^T @ h1 + b2
        #pragma unroll
        for (int Mi = 0; Mi < 4; ++Mi) hacc[Mi] = *(const f4*)(b2 + n*DD + 16*Mi + 4*qd);
        run_stage6(bigp + (size_t)(n*4 + 2)*1024, lane, fh, fl, hacc);
        acc_to_frags1(hacc, fh, fl);   // h2 frags (fp32 recon from hi+lo below)

        // gate logits (pre-scaled by log2e) = Wg'^T @ h2 + bgs
        f4 gacc[4];
        #pragma unroll
        for (int Mi = 0; Mi < 4; ++Mi) gacc[Mi] = *(const f4*)(bgs + n*DD + 16*Mi + 4*qd);
        run_stage6(bigp + (size_t)(n*4 + 3)*1024, lane, fh, fl, gacc);

        // z = h2 * rcp(1 + exp2(-g')) + res
        f4 z[4];
        #pragma unroll
        for (int Mi = 0; Mi < 4; ++Mi) {
            const float h2x = bflo(fh[Mi][0]) + bflo(fl[Mi][0]);
            const float h2y = bfhi(fh[Mi][0]) + bfhi(fl[Mi][0]);
            const float h2z = bflo(fh[Mi][1]) + bflo(fl[Mi][1]);
            const float h2w = bfhi(fh[Mi][1]) + bfhi(fl[Mi][1]);
            const f4 gv = gacc[Mi];
            z[Mi].x = h2x * __builtin_amdgcn_rcpf(1.f + __builtin_amdgcn_exp2f(-gv.x)) + racc[Mi].x;
            z[Mi].y = h2y * __builtin_amdgcn_rcpf(1.f + __builtin_amdgcn_exp2f(-gv.y)) + racc[Mi].y;
            z[Mi].z = h2z * __builtin_amdgcn_rcpf(1.f + __builtin_amdgcn_exp2f(-gv.z)) + racc[Mi].z;
            z[Mi].w = h2w * __builtin_amdgcn_rcpf(1.f + __builtin_amdgcn_exp2f(-gv.w)) + racc[Mi].w;
        }
        // LayerNorm over d (16 in-lane + cross-quad butterfly)
        float s = 0.f;
        #pragma unroll
        for (int Mi = 0; Mi < 4; ++Mi) s += z[Mi].x + z[Mi].y + z[Mi].z + z[Mi].w;
        s += __shfl_xor(s, 16);
        s += __shfl_xor(s, 32);
        const float mu = s * (1.f/64.f);
        float q = 0.f;
        #pragma unroll
        for (int Mi = 0; Mi < 4; ++Mi) {
            float dx = z[Mi].x - mu; q += dx*dx;
            dx = z[Mi].y - mu; q += dx*dx;
            dx = z[Mi].z - mu; q += dx*dx;
            dx = z[Mi].w - mu; q += dx*dx;
        }
        q += __shfl_xor(q, 16);
        q += __shfl_xor(q, 32);
        const float rstd = rsqrtf(q*(1.f/64.f) + LN_EPS);

        const float wn = smem[WSEL_OFF + tq*272 + n*17 + l15];
        #pragma unroll
        for (int Mi = 0; Mi < 4; ++Mi) {
            const f4 gm = *(const f4*)(gamma_ + n*DD + 16*Mi + 4*qd);
            const f4 bb = *(const f4*)(beta_  + n*DD + 16*Mi + 4*qd);
            f4 cb;
            cb.x = wn*((z[Mi].x-mu)*rstd*gm.x + bb.x);
            cb.y = wn*((z[Mi].y-mu)*rstd*gm.y + bb.y);
            cb.z = wn*((z[Mi].z-mu)*rstd*gm.z + bb.z);
            cb.w = wn*((z[Mi].w-mu)*rstd*gm.w + bb.w);
            if (vi == 0) {
                *(f4*)&smem[sbase + 16*Mi] = cb;
            } else {
                const f4 o = *(f4*)&smem[sbase + 16*Mi];
                *(f4*)&smem[sbase + 16*Mi] = o + cb;
            }
        }
    }

    __syncthreads();
    {
        const int tokloc = tid >> 3;            // 0..63 (the 64 tokens of this tile)
        const int d0 = (tid & 7) * 8;
        const int rbase = PSEL_OFF + tokloc*68 + d0;
        const f4 a0 = *(f4*)&smem[rbase];
        const f4 a1 = *(f4*)&smem[rbase + 4];
        const f4 b0 = *(f4*)&smem[rbase + 64*68];
        const f4 b1v = *(f4*)&smem[rbase + 64*68 + 4];
        float* po = out_sel + (size_t)(tile0+tokloc)*DD + d0;
        *(f4*)po     = a0 + b0;
        *(f4*)(po+4) = a1 + b1v;
    }
}

extern "C" void kernel_launch(void* const* d_in, const int* in_sizes, int n_in,
                              void* d_out, int out_size, void* d_ws, size_t ws_size,
                              hipStream_t stream) {
    const float* inp  = (const float*)d_in[0];
    const float* ctx  = (const float*)d_in[1];
    const float* Wt   = (const float*)d_in[2];
    const float* bt   = (const float*)d_in[3];
    const float* Wctx = (const float*)d_in[4];
    const float* W1   = (const float*)d_in[5];
    const float* b1   = (const float*)d_in[6];
    const float* W2   = (const float*)d_in[7];
    const float* b2   = (const float*)d_in[8];
    const float* Wg   = (const float*)d_in[9];
    const float* bg   = (const float*)d_in[10];
    const float* Wp   = (const float*)d_in[11];
    const float* bp   = (const float*)d_in[12];
    const float* gm   = (const float*)d_in[13];
    const float* bt2  = (const float*)d_in[14];
    const float* Ws   = (const float*)d_in[15];
    const float* bs   = (const float*)d_in[16];

    float* out_sel = (float*)d_out;
    float* out_w   = out_sel + (size_t)BT * DD;

    char* ws = (char*)d_ws;
    float* cproj = (float*)(ws + CPROJ_OFF);
    float* rbias = (float*)(ws + RBIAS_OFF);
    u4* wtp  = (u4*)(ws + WTP_OFF);
    u4* bigp = (u4*)(ws + BIGP_OFF);
    u4* wsp  = (u4*)(ws + WSP_OFF);
    float* bgs = (float*)(ws + BGS_OFF);

    prep_kernel<<<406, 256, 0, stream>>>(Wt, W1, W2, Wg, Wp, Ws, ctx, Wctx, bp, bg, bt,
                                         wtp, bigp, wsp, cproj, rbias, bgs);
    vsn_kernel<<<BT / 64, 512, 0, stream>>>(inp, wtp, bigp, wsp,
                                            b1, b2, bgs, rbias, gm, bt2, bs,
                                            cproj, out_sel, out_w);
}

// Round 8
// 224.975 us; speedup vs baseline: 1.5592x; 1.0147x over previous
//
#include <hip/hip_runtime.h>

#define NB 64
#define NT 512
#define NVAR 16
#define VDIM 16
#define DD 64
#define FF 256
#define BT (NB*NT)
#define LN_EPS 1e-3f
#define LOG2E 1.4426950408889634f

typedef __attribute__((ext_vector_type(8))) short bf8;   // 8 bf16 = one MFMA A/B operand
typedef __attribute__((ext_vector_type(4))) float f4;
typedef __attribute__((ext_vector_type(4))) int i4;
typedef __attribute__((ext_vector_type(4))) unsigned u4;

// ---- ws layout (bytes) ----
#define CPROJ_OFF   0                        // 64*16*64 f32 = 256KB  (cproj + bt folded in)
#define RBIAS_OFF   262144                   // 64*16*64 f32 = 256KB  (bp - cproj@Wp)
#define WTP_OFF     524288                   // 16 vars x 4 frags x 64 x 16B = 64KB
#define BIGP_OFF    (524288+65536)           // 16 vars x 4 mats x 16 frags x 64 x 16B = 1MB
#define WSP_OFF     (524288+65536+1048576)   // 16 frags x 64 x 16B = 16KB
#define BGS_OFF     (524288+65536+1048576+16384)      // bgc = log2e*(b2@Wg+bg), 16*64 f32 = 4KB
#define WGC_OFF     (524288+65536+1048576+16384+4096) // Wgc = log2e*W2@Wg, 16*4096 f32 = 256KB
// mats: 0=Wp 1=W1 2=W2 3=Wgc (gate folded through W2; prescaled by log2e)
// bigp frag layout per var-mat (16 frags): idx = (c*2+hl)*4 + Mi
//   c = 32-wide k-chunk (0/1), hl = 0:Wh 1:Wl, Mi = 16-wide m-chunk.
//   lane L holds W[k = 32c + 4(L>>4)+j (j=0..3) and 32c+16+4(L>>4)+j (j=4..7)][m=16Mi+(L&15)]

// ---- precise RNE split (prep-time only) ----
__device__ __forceinline__ void split1(float x, unsigned &hb, float &lo) {
    unsigned u = __builtin_bit_cast(unsigned, x);
    unsigned r = u + 0x7fffu + ((u >> 16) & 1u);
    hb = r >> 16;
    lo = x - __builtin_bit_cast(float, r & 0xffff0000u);
}
__device__ __forceinline__ unsigned rnepk(float x, float y) {
    unsigned a = __builtin_bit_cast(unsigned, x);
    unsigned b = __builtin_bit_cast(unsigned, y);
    a = a + 0x7fffu + ((a >> 16) & 1u);
    b = b + 0x7fffu + ((b >> 16) & 1u);
    return (a >> 16) | (b & 0xffff0000u);
}
__device__ __forceinline__ void split4(f4 v, unsigned &h0, unsigned &h1,
                                       unsigned &l0, unsigned &l1) {
    unsigned b0,b1,b2,b3; float q0,q1,q2,q3;
    split1(v.x,b0,q0); split1(v.y,b1,q1); split1(v.z,b2,q2); split1(v.w,b3,q3);
    h0 = b0 | (b1<<16); h1 = b2 | (b3<<16);
    l0 = rnepk(q0,q1); l1 = rnepk(q2,q3);
}
// ---- fast truncation split (hot path): hi = trunc(x), lo = trunc(x - hi) ----
__device__ __forceinline__ void split4f(f4 v, unsigned &h0, unsigned &h1,
                                        unsigned &l0, unsigned &l1) {
    unsigned a0 = __builtin_bit_cast(unsigned, v.x);
    unsigned a1 = __builtin_bit_cast(unsigned, v.y);
    unsigned a2 = __builtin_bit_cast(unsigned, v.z);
    unsigned a3 = __builtin_bit_cast(unsigned, v.w);
    unsigned m0 = a0 & 0xffff0000u, m1 = a1 & 0xffff0000u;
    unsigned m2 = a2 & 0xffff0000u, m3 = a3 & 0xffff0000u;
    h0 = (a0 >> 16) | m1;
    h1 = (a2 >> 16) | m3;
    float lx = v.x - __builtin_bit_cast(float, m0);
    float ly = v.y - __builtin_bit_cast(float, m1);
    float lz = v.z - __builtin_bit_cast(float, m2);
    float lw = v.w - __builtin_bit_cast(float, m3);
    l0 = (__builtin_bit_cast(unsigned, lx) >> 16) |
         (__builtin_bit_cast(unsigned, ly) & 0xffff0000u);
    l1 = (__builtin_bit_cast(unsigned, lz) >> 16) |
         (__builtin_bit_cast(unsigned, lw) & 0xffff0000u);
}
__device__ __forceinline__ bf8 afrag(u4 w) { return __builtin_bit_cast(bf8, w); }
__device__ __forceinline__ bf8 mk_b4(unsigned w0, unsigned w1, unsigned w2, unsigned w3) {
    i4 t; t.x = (int)w0; t.y = (int)w1; t.z = (int)w2; t.w = (int)w3;
    return __builtin_bit_cast(bf8, t);
}
// legacy duplicated-B operands (Wt stage, K=16 only)
__device__ __forceinline__ bf8 mk_bhh(unsigned h0, unsigned h1) {
    i4 t; t.x = (int)h0; t.y = (int)h1; t.z = (int)h0; t.w = (int)h1;
    return __builtin_bit_cast(bf8, t);
}
__device__ __forceinline__ bf8 mk_bl0(unsigned l0, unsigned l1) {
    i4 t; t.x = (int)l0; t.y = (int)l1; t.z = 0; t.w = 0;
    return __builtin_bit_cast(bf8, t);
}

__device__ __forceinline__ f4 mfma2(f4 acc, bf8 Af, bf8 Bh, bf8 Bl) {
    acc = __builtin_amdgcn_mfma_f32_16x16x32_bf16(Af, Bh, acc, 0,0,0);
    acc = __builtin_amdgcn_mfma_f32_16x16x32_bf16(Af, Bl, acc, 0,0,0);
    return acc;
}

// acc (C-layout) -> B-operand frags of the next stage (pure in-lane repack)
__device__ __forceinline__ void acc_to_frags1(const f4 acc[4],
        unsigned fh[4][2], unsigned fl[4][2]) {
    #pragma unroll
    for (int Ks = 0; Ks < 4; ++Ks)
        split4f(acc[Ks], fh[Ks][0], fh[Ks][1], fl[Ks][0], fl[Ks][1]);
}
// Paired 64x64 GEMM-stage, full-K scheme: both mats consume the SAME B operands.
// 6 MFMAs per Mi per mat; terms kept Wh.xh + Wl.xh + Wh.xl (Wl.xl ~2^-16 dropped).
// All 32 A-loads of the two mats issue at one dependency wall -> max MLP.
__device__ __forceinline__ void run_stage6_pair(const u4* __restrict__ ap0,
        const u4* __restrict__ ap1, int lane,
        const unsigned fh[4][2], const unsigned fl[4][2], f4 acc0[4], f4 acc1[4]) {
    const bf8 Bh0 = mk_b4(fh[0][0], fh[0][1], fh[1][0], fh[1][1]);
    const bf8 Bh1 = mk_b4(fh[2][0], fh[2][1], fh[3][0], fh[3][1]);
    const bf8 Bl0 = mk_b4(fl[0][0], fl[0][1], fl[1][0], fl[1][1]);
    const bf8 Bl1 = mk_b4(fl[2][0], fl[2][1], fl[3][0], fl[3][1]);
    #pragma unroll
    for (int Mi = 0; Mi < 4; ++Mi) {
        {
            const u4 ah0 = ap0[(     Mi)*64 + lane];
            const u4 al0 = ap0[( 4 + Mi)*64 + lane];
            const u4 ah1 = ap0[( 8 + Mi)*64 + lane];
            const u4 al1 = ap0[(12 + Mi)*64 + lane];
            f4 a = acc0[Mi];
            a = __builtin_amdgcn_mfma_f32_16x16x32_bf16(afrag(ah0), Bh0, a, 0,0,0);
            a = __builtin_amdgcn_mfma_f32_16x16x32_bf16(afrag(ah1), Bh1, a, 0,0,0);
            a = __builtin_amdgcn_mfma_f32_16x16x32_bf16(afrag(al0), Bh0, a, 0,0,0);
            a = __builtin_amdgcn_mfma_f32_16x16x32_bf16(afrag(al1), Bh1, a, 0,0,0);
            a = __builtin_amdgcn_mfma_f32_16x16x32_bf16(afrag(ah0), Bl0, a, 0,0,0);
            a = __builtin_amdgcn_mfma_f32_16x16x32_bf16(afrag(ah1), Bl1, a, 0,0,0);
            acc0[Mi] = a;
        }
        {
            const u4 ah0 = ap1[(     Mi)*64 + lane];
            const u4 al0 = ap1[( 4 + Mi)*64 + lane];
            const u4 ah1 = ap1[( 8 + Mi)*64 + lane];
            const u4 al1 = ap1[(12 + Mi)*64 + lane];
            f4 a = acc1[Mi];
            a = __builtin_amdgcn_mfma_f32_16x16x32_bf16(afrag(ah0), Bh0, a, 0,0,0);
            a = __builtin_amdgcn_mfma_f32_16x16x32_bf16(afrag(ah1), Bh1, a, 0,0,0);
            a = __builtin_amdgcn_mfma_f32_16x16x32_bf16(afrag(al0), Bh0, a, 0,0,0);
            a = __builtin_amdgcn_mfma_f32_16x16x32_bf16(afrag(al1), Bh1, a, 0,0,0);
            a = __builtin_amdgcn_mfma_f32_16x16x32_bf16(afrag(ah0), Bl0, a, 0,0,0);
            a = __builtin_amdgcn_mfma_f32_16x16x32_bf16(afrag(ah1), Bl1, a, 0,0,0);
            acc1[Mi] = a;
        }
    }
}

// prep0: fold the gate through W2 (fp32, exact dots):
//   wgc[n][d][f] = LOG2E * sum_e W2[n][d][e]*Wg[n][e][f]
//   bgc[n][f]    = LOG2E * (sum_e b2[n][e]*Wg[n][e][f] + bg[n][f])
// 64 blocks: var = bid>>2, k-quarter = bid&3. Wg staged in LDS.
__global__ void prep0_kernel(const float* __restrict__ W2, const float* __restrict__ Wg,
                             const float* __restrict__ b2, const float* __restrict__ bg,
                             float* __restrict__ wgc, float* __restrict__ bgc) {
    __shared__ float wg[4096];
    const int var = blockIdx.x >> 2;
    const int kb  = (blockIdx.x & 3) * 16;
    const float* wgsrc = Wg + var * 4096;
    #pragma unroll
    for (int i = 0; i < 16; ++i) wg[i*256 + threadIdx.x] = wgsrc[i*256 + threadIdx.x];
    __syncthreads();
    const int m  = threadIdx.x & 63;
    const int ks = threadIdx.x >> 6;            // 0..3
    const float* w2 = W2 + var * 4096;
    #pragma unroll
    for (int kk = 0; kk < 4; ++kk) {
        const int k = kb + ks * 4 + kk;
        float acc = 0.f;
        #pragma unroll 8
        for (int e = 0; e < 64; ++e) acc += w2[k*64 + e] * wg[e*64 + m];
        wgc[(size_t)var*4096 + k*64 + m] = LOG2E * acc;
    }
    if ((blockIdx.x & 3) == 0 && threadIdx.x < 64) {
        float acc = bg[var*64 + m];
        #pragma unroll 8
        for (int e = 0; e < 64; ++e) acc += b2[var*64 + e] * wg[e*64 + m];
        bgc[var*64 + m] = LOG2E * acc;
    }
}

// Prep: weight pack (blocks 0..149) + cproj/rbias (blocks 150..405).
// mat 3 packs wgc (already log2e-scaled by prep0).
__global__ void prep_kernel(const float* __restrict__ Wt, const float* __restrict__ W1,
                            const float* __restrict__ W2, const float* __restrict__ Wgc,
                            const float* __restrict__ Wp, const float* __restrict__ Ws,
                            const float* __restrict__ ctx, const float* __restrict__ Wctx,
                            const float* __restrict__ bp, const float* __restrict__ bt,
                            u4* __restrict__ wtp, u4* __restrict__ bigp,
                            u4* __restrict__ wsp, float* __restrict__ cproj,
                            float* __restrict__ rbias) {
    if (blockIdx.x >= 150) {
        __shared__ float cp[4][64];
        const int sub = threadIdx.x >> 6, d = threadIdx.x & 63;
        const int bn = (blockIdx.x - 150) * 4 + sub;
        const int b = bn >> 4, n = bn & 15;
        const float* __restrict__ wc = Wctx + n * DD * DD;
        const float* __restrict__ c  = ctx + b * DD;
        float acc = 0.f;
        #pragma unroll 8
        for (int k = 0; k < DD; ++k) acc += c[k] * wc[k * DD + d];
        cproj[bn * DD + d] = acc + bt[n * DD + d];   // bt folded in for vsn
        cp[sub][d] = acc;                            // un-biased copy for rbias
        __syncthreads();
        const float* __restrict__ wp = Wp + n * DD * DD;
        float r = bp[n * DD + d];
        #pragma unroll 8
        for (int k = 0; k < DD; ++k) r -= cp[sub][k] * wp[k * DD + d];
        rbias[bn * DD + d] = r;
        return;
    }
    const int t = blockIdx.x * 256 + threadIdx.x;
    if (t < 32768) {
        // big mats: per thread one (var,mat,c,Mi) h-frag + l-frag (8 source floats)
        const int lane = t & 63, Mi = (t>>6)&3, c = (t>>8)&1, mat = (t>>9)&3, var = t>>11;
        const float* W = (mat==0) ? Wp : (mat==1) ? W1 : (mat==2) ? W2 : Wgc;
        const float* src = W + var*4096;
        const int m = 16*Mi + (lane&15), q = lane>>4;
        const int k0 = 32*c + 4*q;
        unsigned hb[8]; float lo[8];
        #pragma unroll
        for (int j = 0; j < 4; ++j) split1(src[(k0+j)*64+m],    hb[j],   lo[j]);
        #pragma unroll
        for (int j = 0; j < 4; ++j) split1(src[(k0+16+j)*64+m], hb[4+j], lo[4+j]);
        u4 hf, lf;
        hf.x = hb[0]|(hb[1]<<16); hf.y = hb[2]|(hb[3]<<16);
        hf.z = hb[4]|(hb[5]<<16); hf.w = hb[6]|(hb[7]<<16);
        lf.x = rnepk(lo[0],lo[1]); lf.y = rnepk(lo[2],lo[3]);
        lf.z = rnepk(lo[4],lo[5]); lf.w = rnepk(lo[6],lo[7]);
        u4* base = bigp + (size_t)((var*4+mat)*16)*64;
        base[((c*2+0)*4 + Mi)*64 + lane] = hf;
        base[((c*2+1)*4 + Mi)*64 + lane] = lf;
    } else if (t < 36864) {
        // Wt: legacy [Wh|Wl] frag (K=16 stage keeps duplicated-B mfma2)
        const int r = t - 32768;
        const int lane = r & 63, Mi = (r>>6)&3, var = r>>8;
        const int m = 16*Mi + (lane&15), k0 = 4*(lane>>4);
        const float* src = Wt + var*1024;
        f4 v;
        v.x = src[(k0+0)*64+m]; v.y = src[(k0+1)*64+m];
        v.z = src[(k0+2)*64+m]; v.w = src[(k0+3)*64+m];
        unsigned h0,h1,l0,l1; split4(v,h0,h1,l0,l1);
        u4 o; o.x=h0; o.y=h1; o.z=l0; o.w=l1;
        wtp[(var*4+Mi)*64 + lane] = o;
    } else if (t < 37376) {
        // Ws: full-K chunks (c=0..7), h-frag + l-frag per thread
        const int r = t - 36864;
        const int lane = r & 63, c = r >> 6;
        const int n = lane & 15, q = lane >> 4;
        const int k0 = 32*c + 4*q;
        unsigned hb[8]; float lo[8];
        #pragma unroll
        for (int j = 0; j < 4; ++j) split1(Ws[(k0+j)*16+n],    hb[j],   lo[j]);
        #pragma unroll
        for (int j = 0; j < 4; ++j) split1(Ws[(k0+16+j)*16+n], hb[4+j], lo[4+j]);
        u4 hf, lf;
        hf.x = hb[0]|(hb[1]<<16); hf.y = hb[2]|(hb[3]<<16);
        hf.z = hb[4]|(hb[5]<<16); hf.w = hb[6]|(hb[7]<<16);
        lf.x = rnepk(lo[0],lo[1]); lf.y = rnepk(lo[2],lo[3]);
        lf.z = rnepk(lo[4],lo[5]); lf.w = rnepk(lo[6],lo[7]);
        wsp[(c*2+0)*64 + lane] = hf;
        wsp[(c*2+1)*64 + lane] = lf;
    }
}

// Main: block = 512 threads = 8 waves, 64 tokens; grid = 512 (R0 skeleton).
// REGISTER-CAP LEDGER (hard-won):
//   cap 128, R0 body (8-MFMA, sel in regs)          -> fits, 143.6us.
//   cap 128, R7 body (pair+6-MFMA, sel in LDS)      -> fits, 140.5us.
//   cap 128, R6 body (pair+6-MFMA, sel in REGS)     -> SPILLS 503MB, 264us.
//   cap <128 (R1/R4)                                -> catastrophic spills.
// R7 LESSON: removing 41us of pipe work bought only 3us -> latency-bound at
// 3.4 waves/SIMD; the stall is the serial GEMM-stage walls (16 dependent L2
// loads each, ~200cy). THIS ROUND: fold the gate through W2 at prep
// (Wgc = log2e*W2@Wg, bgc = log2e*(b2@Wg+bg)) so W2 and the gate become a
// shared-B pair on the h1 frags: 4 walls/var -> 3, 32 loads per wall (2x MLP),
// h2 stays fp32 (no split/recon). Same MFMA count.
#define PSEL_OFF 0          // 128 rows (grp*64+tq*16+l15) x 68 dw = 8704 dw
#define WSEL_OFF 8704       // 4 tq x 16 n x 17 = 1088 dw
#define SMEM_DW  9792       // 39168 B; 2 blocks/CU = 78KB <= 160KB

__global__ __launch_bounds__(512, 4)
void vsn_kernel(const float* __restrict__ inp,
                const u4* __restrict__ wtp, const u4* __restrict__ bigp,
                const u4* __restrict__ wsp,
                const float* __restrict__ b1,
                const float* __restrict__ b2, const float* __restrict__ bgc,
                const float* __restrict__ rbias,
                const float* __restrict__ gamma_, const float* __restrict__ beta_,
                const float* __restrict__ bs,
                const float* __restrict__ cprojb,
                float* __restrict__ out_sel, float* __restrict__ out_w) {
    __shared__ float smem[SMEM_DW];

    const int tid  = threadIdx.x;
    const int lane = tid & 63;
    const int wv   = tid >> 6;
    const int grp  = wv & 1;                    // var group (8 vars)
    const int tq   = wv >> 1;                   // token quarter (16 tokens)
    const int qd   = lane >> 4;
    const int l15  = lane & 15;
    const int tile0 = blockIdx.x * 64;
    const int b     = blockIdx.x >> 3;          // tile0 / NT
    const int tok0  = tile0 + tq * 16;

    const float* row = inp + (size_t)(tok0 + l15) * FF;   // my token's feature row

    // ---------------- logits via MFMA + softmax (per wave, 16 tokens) -------
    {
        f4 lacc = *(const f4*)(bs + 4*qd);      // n = 4*qd + reg
        #pragma unroll 4
        for (int c = 0; c < 8; ++c) {
            const u4 wh = wsp[(c*2+0)*64 + lane];
            const u4 wl = wsp[(c*2+1)*64 + lane];
            const f4 v1 = *(const f4*)(row + 32*c + 4*qd);
            const f4 v2 = *(const f4*)(row + 32*c + 16 + 4*qd);
            unsigned h0,h1,l0,l1,h2,h3,l2,l3;
            split4f(v1,h0,h1,l0,l1);
            split4f(v2,h2,h3,l2,l3);
            const bf8 Bh = mk_b4(h0,h1,h2,h3);
            const bf8 Bl = mk_b4(l0,l1,l2,l3);
            lacc = __builtin_amdgcn_mfma_f32_16x16x32_bf16(afrag(wh), Bh, lacc, 0,0,0);
            lacc = __builtin_amdgcn_mfma_f32_16x16x32_bf16(afrag(wl), Bh, lacc, 0,0,0);
            lacc = __builtin_amdgcn_mfma_f32_16x16x32_bf16(afrag(wh), Bl, lacc, 0,0,0);
        }
        float mx = fmaxf(fmaxf(lacc.x,lacc.y), fmaxf(lacc.z,lacc.w));
        mx = fmaxf(mx, __shfl_xor(mx, 16));
        mx = fmaxf(mx, __shfl_xor(mx, 32));
        float e0 = __expf(lacc.x-mx), e1 = __expf(lacc.y-mx);
        float e2 = __expf(lacc.z-mx), e3 = __expf(lacc.w-mx);
        float s = e0+e1+e2+e3;
        s += __shfl_xor(s, 16);
        s += __shfl_xor(s, 32);
        const float rs = __builtin_amdgcn_rcpf(s);
        e0 *= rs; e1 *= rs; e2 *= rs; e3 *= rs;
        // both grp waves of a tq write identical bits -> benign duplicate;
        // each wave reads only rows its own lanes wrote -> no barrier.
        const int base = WSEL_OFF + tq*272 + (4*qd)*17 + l15;
        smem[base + 0*17] = e0;
        smem[base + 1*17] = e1;
        smem[base + 2*17] = e2;
        smem[base + 3*17] = e3;
        if (grp == 0) {
            f4 o; o.x=e0; o.y=e1; o.z=e2; o.w=e3;
            *(f4*)(out_w + (size_t)(tok0 + l15)*16 + 4*qd) = o;
        }
    }

    // ---------------- per-variable GRN chain (8 vars per wave) --------------
    // sel accumulates in LDS (lane-private row chunks; no races, no barrier):
    // keeps the paired body under the 128-reg cap (see ledger).
    const int sbase = PSEL_OFF + (grp*64 + tq*16 + l15)*68 + 4*qd;

    #pragma unroll 1
    for (int vi = 0; vi < 8; ++vi) {
        const int n = grp*8 + vi;
        unsigned fh[4][2], fl[4][2];

        // a = Wt^T @ xv + (bt + cproj)  [bt folded into cprojb at prep time]
        f4 tacc[4];
        #pragma unroll
        for (int Mi = 0; Mi < 4; ++Mi)
            tacc[Mi] = *(const f4*)(cprojb + (size_t)(b*NVAR+n)*DD + 16*Mi + 4*qd);
        {
            const f4 v = *(const f4*)(row + n*16 + 4*qd);
            unsigned xh0,xh1,xl0,xl1;
            split4f(v, xh0, xh1, xl0, xl1);
            const bf8 Bh = mk_bhh(xh0, xh1);
            const bf8 Bl = mk_bl0(xl0, xl1);
            #pragma unroll
            for (int Mi = 0; Mi < 4; ++Mi) {
                const u4 w = wtp[(n*4+Mi)*64 + lane];
                tacc[Mi] = mfma2(tacc[Mi], afrag(w), Bh, Bl);
            }
        }
        acc_to_frags1(tacc, fh, fl);   // a-frags

        // wall 2: res = Wp^T a + rbias ; h1pre = W1^T a + b1  (shared a-frags)
        f4 racc[4], hacc[4];
        #pragma unroll
        for (int Mi = 0; Mi < 4; ++Mi) {
            racc[Mi] = *(const f4*)(rbias + (size_t)(b*NVAR+n)*DD + 16*Mi + 4*qd);
            hacc[Mi] = *(const f4*)(b1 + n*DD + 16*Mi + 4*qd);
        }
        run_stage6_pair(bigp + (size_t)(n*4 + 0)*1024,
                        bigp + (size_t)(n*4 + 1)*1024, lane, fh, fl, racc, hacc);
        #pragma unroll
        for (int Mi = 0; Mi < 4; ++Mi) {
            f4& v = hacc[Mi];
            v.x = v.x > 0.f ? v.x : (__expf(v.x)-1.f);
            v.y = v.y > 0.f ? v.y : (__expf(v.y)-1.f);
            v.z = v.z > 0.f ? v.z : (__expf(v.z)-1.f);
            v.w = v.w > 0.f ? v.w : (__expf(v.w)-1.f);
        }
        acc_to_frags1(hacc, fh, fl);   // h1 frags

        // wall 3: h2 = W2^T h1 + b2 ; g' = Wgc^T h1 + bgc  (shared h1-frags;
        // gate pre-folded through W2 at prep). h2 stays fp32 — no recon.
        f4 gacc[4];
        #pragma unroll
        for (int Mi = 0; Mi < 4; ++Mi) {
            hacc[Mi] = *(const f4*)(b2  + n*DD + 16*Mi + 4*qd);
            gacc[Mi] = *(const f4*)(bgc + n*DD + 16*Mi + 4*qd);
        }
        run_stage6_pair(bigp + (size_t)(n*4 + 2)*1024,
                        bigp + (size_t)(n*4 + 3)*1024, lane, fh, fl, hacc, gacc);

        // z = h2 * rcp(1 + exp2(-g')) + res
        f4 z[4];
        #pragma unroll
        for (int Mi = 0; Mi < 4; ++Mi) {
            const f4 gv = gacc[Mi];
            z[Mi].x = hacc[Mi].x * __builtin_amdgcn_rcpf(1.f + __builtin_amdgcn_exp2f(-gv.x)) + racc[Mi].x;
            z[Mi].y = hacc[Mi].y * __builtin_amdgcn_rcpf(1.f + __builtin_amdgcn_exp2f(-gv.y)) + racc[Mi].y;
            z[Mi].z = hacc[Mi].z * __builtin_amdgcn_rcpf(1.f + __builtin_amdgcn_exp2f(-gv.z)) + racc[Mi].z;
            z[Mi].w = hacc[Mi].w * __builtin_amdgcn_rcpf(1.f + __builtin_amdgcn_exp2f(-gv.w)) + racc[Mi].w;
        }
        // LayerNorm over d (16 in-lane + cross-quad butterfly)
        float s = 0.f;
        #pragma unroll
        for (int Mi = 0; Mi < 4; ++Mi) s += z[Mi].x + z[Mi].y + z[Mi].z + z[Mi].w;
        s += __shfl_xor(s, 16);
        s += __shfl_xor(s, 32);
        const float mu = s * (1.f/64.f);
        float q = 0.f;
        #pragma unroll
        for (int Mi = 0; Mi < 4; ++Mi) {
            float dx = z[Mi].x - mu; q += dx*dx;
            dx = z[Mi].y - mu; q += dx*dx;
            dx = z[Mi].z - mu; q += dx*dx;
            dx = z[Mi].w - mu; q += dx*dx;
        }
        q += __shfl_xor(q, 16);
        q += __shfl_xor(q, 32);
        const float rstd = rsqrtf(q*(1.f/64.f) + LN_EPS);

        const float wn = smem[WSEL_OFF + tq*272 + n*17 + l15];
        #pragma unroll
        for (int Mi = 0; Mi < 4; ++Mi) {
            const f4 gm = *(const f4*)(gamma_ + n*DD + 16*Mi + 4*qd);
            const f4 bb = *(const f4*)(beta_  + n*DD + 16*Mi + 4*qd);
            f4 cb;
            cb.x = wn*((z[Mi].x-mu)*rstd*gm.x + bb.x);
            cb.y = wn*((z[Mi].y-mu)*rstd*gm.y + bb.y);
            cb.z = wn*((z[Mi].z-mu)*rstd*gm.z + bb.z);
            cb.w = wn*((z[Mi].w-mu)*rstd*gm.w + bb.w);
            if (vi == 0) {
                *(f4*)&smem[sbase + 16*Mi] = cb;
            } else {
                const f4 o = *(f4*)&smem[sbase + 16*Mi];
                *(f4*)&smem[sbase + 16*Mi] = o + cb;
            }
        }
    }

    __syncthreads();
    {
        const int tokloc = tid >> 3;            // 0..63 (the 64 tokens of this tile)
        const int d0 = (tid & 7) * 8;
        const int rbase = PSEL_OFF + tokloc*68 + d0;
        const f4 a0 = *(f4*)&smem[rbase];
        const f4 a1 = *(f4*)&smem[rbase + 4];
        const f4 b0 = *(f4*)&smem[rbase + 64*68];
        const f4 b1v = *(f4*)&smem[rbase + 64*68 + 4];
        float* po = out_sel + (size_t)(tile0+tokloc)*DD + d0;
        *(f4*)po     = a0 + b0;
        *(f4*)(po+4) = a1 + b1v;
    }
}

extern "C" void kernel_launch(void* const* d_in, const int* in_sizes, int n_in,
                              void* d_out, int out_size, void* d_ws, size_t ws_size,
                              hipStream_t stream) {
    const float* inp  = (const float*)d_in[0];
    const float* ctx  = (const float*)d_in[1];
    const float* Wt   = (const float*)d_in[2];
    const float* bt   = (const float*)d_in[3];
    const float* Wctx = (const float*)d_in[4];
    const float* W1   = (const float*)d_in[5];
    const float* b1   = (const float*)d_in[6];
    const float* W2   = (const float*)d_in[7];
    const float* b2   = (const float*)d_in[8];
    const float* Wg   = (const float*)d_in[9];
    const float* bg   = (const float*)d_in[10];
    const float* Wp   = (const float*)d_in[11];
    const float* bp   = (const float*)d_in[12];
    const float* gm   = (const float*)d_in[13];
    const float* bt2  = (const float*)d_in[14];
    const float* Ws   = (const float*)d_in[15];
    const float* bs   = (const float*)d_in[16];

    float* out_sel = (float*)d_out;
    float* out_w   = out_sel + (size_t)BT * DD;

    char* ws = (char*)d_ws;
    float* cproj = (float*)(ws + CPROJ_OFF);
    float* rbias = (float*)(ws + RBIAS_OFF);
    u4* wtp  = (u4*)(ws + WTP_OFF);
    u4* bigp = (u4*)(ws + BIGP_OFF);
    u4* wsp  = (u4*)(ws + WSP_OFF);
    float* bgc = (float*)(ws + BGS_OFF);
    float* wgc = (float*)(ws + WGC_OFF);

    prep0_kernel<<<64, 256, 0, stream>>>(W2, Wg, b2, bg, wgc, bgc);
    prep_kernel<<<406, 256, 0, stream>>>(Wt, W1, W2, wgc, Wp, Ws, ctx, Wctx, bp, bt,
                                         wtp, bigp, wsp, cproj, rbias);
    vsn_kernel<<<BT / 64, 512, 0, stream>>>(inp, wtp, bigp, wsp,
                                            b1, b2, bgc, rbias, gm, bt2, bs,
                                            cproj, out_sel, out_w);
}

// Round 9
// 193.050 us; speedup vs baseline: 1.8171x; 1.1654x over previous
//
#include <hip/hip_runtime.h>

#define NB 64
#define NT 512
#define NVAR 16
#define VDIM 16
#define DD 64
#define FF 256
#define BT (NB*NT)
#define LN_EPS 1e-3f
#define LOG2E 1.4426950408889634f

typedef __attribute__((ext_vector_type(8))) short bf8;   // 8 bf16 = one MFMA A/B operand
typedef __attribute__((ext_vector_type(4))) float f4;
typedef __attribute__((ext_vector_type(4))) int i4;
typedef __attribute__((ext_vector_type(4))) unsigned u4;

// ---- ws layout (bytes) ----
// ALGEBRAIC FOLDS (all exact fp32 at prep):
//   rpb[n]     = bt@Wp + bp                      (res bias, per var)
//   cpb1[b][n] = (ctx@Wctx + bt)@W1 + b1         (h1 bias, per batch-var)
//   wtpf       = Wt@Wp, wt1f = Wt@W1             (K=16 mats off xv)
//   wgcf       = log2e*W2@Wg, bgc = log2e*(b2@Wg+bg)  (gate through W2)
// vsn walls per var: A) [wtpf|wt1f] K=16 pair off xv  B) [W2|wgcf] K=64 pair off h1.
#define CPB1_OFF   0                  // 64*16*64 f32 = 256KB
#define RPB_OFF    262144             // 16*64 f32 = 4KB
#define WTPP_OFF   266240             // packed Wt@Wp: 16v x 4Mi x 64 x 16B = 64KB
#define WT1P_OFF   331776             // packed Wt@W1: 64KB
#define BIGP_OFF   397312             // 2 mats x 16v x 16 frags x 64 x 16B = 512KB
#define WSP_OFF    921600             // 16 frags x 64 x 16B = 16KB
#define BGC_OFF    937984             // 16*64 f32 = 4KB
#define WGCF_OFF   942080             // wgc float intermediate 256KB
#define WTPF_OFF   1204224            // Wt@Wp float intermediate 64KB
#define WT1F_OFF   1269760            // Wt@W1 float intermediate 64KB
// bigp frag layout per var-mat (16 frags): idx = (c*2+hl)*4 + Mi ; mats 0=W2 1=wgcf

// ---- precise RNE split (prep-time only) ----
__device__ __forceinline__ void split1(float x, unsigned &hb, float &lo) {
    unsigned u = __builtin_bit_cast(unsigned, x);
    unsigned r = u + 0x7fffu + ((u >> 16) & 1u);
    hb = r >> 16;
    lo = x - __builtin_bit_cast(float, r & 0xffff0000u);
}
__device__ __forceinline__ unsigned rnepk(float x, float y) {
    unsigned a = __builtin_bit_cast(unsigned, x);
    unsigned b = __builtin_bit_cast(unsigned, y);
    a = a + 0x7fffu + ((a >> 16) & 1u);
    b = b + 0x7fffu + ((b >> 16) & 1u);
    return (a >> 16) | (b & 0xffff0000u);
}
__device__ __forceinline__ void split4(f4 v, unsigned &h0, unsigned &h1,
                                       unsigned &l0, unsigned &l1) {
    unsigned b0,b1,b2,b3; float q0,q1,q2,q3;
    split1(v.x,b0,q0); split1(v.y,b1,q1); split1(v.z,b2,q2); split1(v.w,b3,q3);
    h0 = b0 | (b1<<16); h1 = b2 | (b3<<16);
    l0 = rnepk(q0,q1); l1 = rnepk(q2,q3);
}
// ---- fast truncation split (hot path): hi = trunc(x), lo = trunc(x - hi) ----
__device__ __forceinline__ void split4f(f4 v, unsigned &h0, unsigned &h1,
                                        unsigned &l0, unsigned &l1) {
    unsigned a0 = __builtin_bit_cast(unsigned, v.x);
    unsigned a1 = __builtin_bit_cast(unsigned, v.y);
    unsigned a2 = __builtin_bit_cast(unsigned, v.z);
    unsigned a3 = __builtin_bit_cast(unsigned, v.w);
    unsigned m0 = a0 & 0xffff0000u, m1 = a1 & 0xffff0000u;
    unsigned m2 = a2 & 0xffff0000u, m3 = a3 & 0xffff0000u;
    h0 = (a0 >> 16) | m1;
    h1 = (a2 >> 16) | m3;
    float lx = v.x - __builtin_bit_cast(float, m0);
    float ly = v.y - __builtin_bit_cast(float, m1);
    float lz = v.z - __builtin_bit_cast(float, m2);
    float lw = v.w - __builtin_bit_cast(float, m3);
    l0 = (__builtin_bit_cast(unsigned, lx) >> 16) |
         (__builtin_bit_cast(unsigned, ly) & 0xffff0000u);
    l1 = (__builtin_bit_cast(unsigned, lz) >> 16) |
         (__builtin_bit_cast(unsigned, lw) & 0xffff0000u);
}
__device__ __forceinline__ bf8 afrag(u4 w) { return __builtin_bit_cast(bf8, w); }
__device__ __forceinline__ bf8 mk_b4(unsigned w0, unsigned w1, unsigned w2, unsigned w3) {
    i4 t; t.x = (int)w0; t.y = (int)w1; t.z = (int)w2; t.w = (int)w3;
    return __builtin_bit_cast(bf8, t);
}
// duplicated-B operands (K=16 stages)
__device__ __forceinline__ bf8 mk_bhh(unsigned h0, unsigned h1) {
    i4 t; t.x = (int)h0; t.y = (int)h1; t.z = (int)h0; t.w = (int)h1;
    return __builtin_bit_cast(bf8, t);
}
__device__ __forceinline__ bf8 mk_bl0(unsigned l0, unsigned l1) {
    i4 t; t.x = (int)l0; t.y = (int)l1; t.z = 0; t.w = 0;
    return __builtin_bit_cast(bf8, t);
}

__device__ __forceinline__ f4 mfma2(f4 acc, bf8 Af, bf8 Bh, bf8 Bl) {
    acc = __builtin_amdgcn_mfma_f32_16x16x32_bf16(Af, Bh, acc, 0,0,0);
    acc = __builtin_amdgcn_mfma_f32_16x16x32_bf16(Af, Bl, acc, 0,0,0);
    return acc;
}

// acc (C-layout) -> B-operand frags of the next stage (pure in-lane repack)
__device__ __forceinline__ void acc_to_frags1(const f4 acc[4],
        unsigned fh[4][2], unsigned fl[4][2]) {
    #pragma unroll
    for (int Ks = 0; Ks < 4; ++Ks)
        split4f(acc[Ks], fh[Ks][0], fh[Ks][1], fl[Ks][0], fl[Ks][1]);
}
// Paired 64x64 GEMM-stage, full-K: both mats consume the SAME B operands.
// 6 MFMAs per Mi per mat; terms Wh.xh + Wl.xh + Wh.xl (Wl.xl ~2^-16 dropped).
__device__ __forceinline__ void run_stage6_pair(const u4* __restrict__ ap0,
        const u4* __restrict__ ap1, int lane,
        const unsigned fh[4][2], const unsigned fl[4][2], f4 acc0[4], f4 acc1[4]) {
    const bf8 Bh0 = mk_b4(fh[0][0], fh[0][1], fh[1][0], fh[1][1]);
    const bf8 Bh1 = mk_b4(fh[2][0], fh[2][1], fh[3][0], fh[3][1]);
    const bf8 Bl0 = mk_b4(fl[0][0], fl[0][1], fl[1][0], fl[1][1]);
    const bf8 Bl1 = mk_b4(fl[2][0], fl[2][1], fl[3][0], fl[3][1]);
    #pragma unroll
    for (int Mi = 0; Mi < 4; ++Mi) {
        {
            const u4 ah0 = ap0[(     Mi)*64 + lane];
            const u4 al0 = ap0[( 4 + Mi)*64 + lane];
            const u4 ah1 = ap0[( 8 + Mi)*64 + lane];
            const u4 al1 = ap0[(12 + Mi)*64 + lane];
            f4 a = acc0[Mi];
            a = __builtin_amdgcn_mfma_f32_16x16x32_bf16(afrag(ah0), Bh0, a, 0,0,0);
            a = __builtin_amdgcn_mfma_f32_16x16x32_bf16(afrag(ah1), Bh1, a, 0,0,0);
            a = __builtin_amdgcn_mfma_f32_16x16x32_bf16(afrag(al0), Bh0, a, 0,0,0);
            a = __builtin_amdgcn_mfma_f32_16x16x32_bf16(afrag(al1), Bh1, a, 0,0,0);
            a = __builtin_amdgcn_mfma_f32_16x16x32_bf16(afrag(ah0), Bl0, a, 0,0,0);
            a = __builtin_amdgcn_mfma_f32_16x16x32_bf16(afrag(ah1), Bl1, a, 0,0,0);
            acc0[Mi] = a;
        }
        {
            const u4 ah0 = ap1[(     Mi)*64 + lane];
            const u4 al0 = ap1[( 4 + Mi)*64 + lane];
            const u4 ah1 = ap1[( 8 + Mi)*64 + lane];
            const u4 al1 = ap1[(12 + Mi)*64 + lane];
            f4 a = acc1[Mi];
            a = __builtin_amdgcn_mfma_f32_16x16x32_bf16(afrag(ah0), Bh0, a, 0,0,0);
            a = __builtin_amdgcn_mfma_f32_16x16x32_bf16(afrag(ah1), Bh1, a, 0,0,0);
            a = __builtin_amdgcn_mfma_f32_16x16x32_bf16(afrag(al0), Bh0, a, 0,0,0);
            a = __builtin_amdgcn_mfma_f32_16x16x32_bf16(afrag(al1), Bh1, a, 0,0,0);
            a = __builtin_amdgcn_mfma_f32_16x16x32_bf16(afrag(ah0), Bl0, a, 0,0,0);
            a = __builtin_amdgcn_mfma_f32_16x16x32_bf16(afrag(ah1), Bl1, a, 0,0,0);
            acc1[Mi] = a;
        }
    }
}

// prep0: all fp32 folds.
// blocks 0..63:  var=bid>>2, quarter: wgcf = log2e*W2@Wg (+ bgc on quarter 0)
// blocks 64..79: var=bid-64: wtpf = Wt@Wp, wt1f = Wt@W1, rpb = bt@Wp + bp
__global__ void prep0_kernel(const float* __restrict__ Wt, const float* __restrict__ W1,
                             const float* __restrict__ W2, const float* __restrict__ Wg,
                             const float* __restrict__ Wp,
                             const float* __restrict__ b2, const float* __restrict__ bg,
                             const float* __restrict__ bt, const float* __restrict__ bp,
                             float* __restrict__ wgcf, float* __restrict__ bgc,
                             float* __restrict__ wtpf, float* __restrict__ wt1f,
                             float* __restrict__ rpb) {
    __shared__ float sh[9216];
    const int tid = threadIdx.x;
    if (blockIdx.x < 64) {
        const int var = blockIdx.x >> 2;
        const int kb  = (blockIdx.x & 3) * 16;
        const float* wgsrc = Wg + var * 4096;
        #pragma unroll
        for (int i = 0; i < 16; ++i) sh[i*256 + tid] = wgsrc[i*256 + tid];
        __syncthreads();
        const int m  = tid & 63;
        const int ks = tid >> 6;            // 0..3
        const float* w2 = W2 + var * 4096;
        #pragma unroll
        for (int kk = 0; kk < 4; ++kk) {
            const int k = kb + ks * 4 + kk;
            float acc = 0.f;
            #pragma unroll 8
            for (int e = 0; e < 64; ++e) acc += w2[k*64 + e] * sh[e*64 + m];
            wgcf[(size_t)var*4096 + k*64 + m] = LOG2E * acc;
        }
        if ((blockIdx.x & 3) == 0 && tid < 64) {
            float acc = bg[var*64 + m];
            #pragma unroll 8
            for (int e = 0; e < 64; ++e) acc += b2[var*64 + e] * sh[e*64 + m];
            bgc[var*64 + m] = LOG2E * acc;
        }
        return;
    }
    const int var = blockIdx.x - 64;
    // sh: [0..4095] = Wp[var], [4096..8191] = W1[var], [8192..9215] = Wt[var]
    const float* wpsrc = Wp + var * 4096;
    const float* w1src = W1 + var * 4096;
    const float* wtsrc = Wt + var * 1024;
    #pragma unroll
    for (int i = 0; i < 16; ++i) sh[i*256 + tid]        = wpsrc[i*256 + tid];
    #pragma unroll
    for (int i = 0; i < 16; ++i) sh[4096 + i*256 + tid] = w1src[i*256 + tid];
    #pragma unroll
    for (int i = 0; i < 4; ++i)  sh[8192 + i*256 + tid] = wtsrc[i*256 + tid];
    __syncthreads();
    const int m  = tid & 63;
    const int vq = tid >> 6;                // 0..3
    #pragma unroll
    for (int vv = 0; vv < 4; ++vv) {
        const int v = vq*4 + vv;
        float ap = 0.f, a1 = 0.f;
        #pragma unroll 8
        for (int d = 0; d < 64; ++d) {
            const float w = sh[8192 + v*64 + d];
            ap += w * sh[d*64 + m];
            a1 += w * sh[4096 + d*64 + m];
        }
        wtpf[(size_t)var*1024 + v*64 + m] = ap;
        wt1f[(size_t)var*1024 + v*64 + m] = a1;
    }
    if (tid < 64) {
        float acc = bp[var*64 + tid];
        #pragma unroll 8
        for (int d = 0; d < 64; ++d) acc += bt[var*64 + d] * sh[d*64 + tid];
        rpb[var*64 + tid] = acc;
    }
}

// prep: pack (blocks 0..97) + context cpb1 (blocks 98..353).
__global__ void prep_kernel(const float* __restrict__ W2, const float* __restrict__ wgcf,
                            const float* __restrict__ wtpf, const float* __restrict__ wt1f,
                            const float* __restrict__ Ws,
                            const float* __restrict__ ctx, const float* __restrict__ Wctx,
                            const float* __restrict__ bt, const float* __restrict__ b1,
                            const float* __restrict__ W1,
                            u4* __restrict__ wtpp, u4* __restrict__ wt1p,
                            u4* __restrict__ bigp, u4* __restrict__ wsp,
                            float* __restrict__ cpb1) {
    if (blockIdx.x >= 98) {
        // cpb1[b][n][d] = (ctx@Wctx + bt)@W1 + b1  (fp32)
        __shared__ float cp[4][64];
        const int sub = threadIdx.x >> 6, d = threadIdx.x & 63;
        const int bn = (blockIdx.x - 98) * 4 + sub;
        const int b = bn >> 4, n = bn & 15;
        const float* __restrict__ wc = Wctx + n * DD * DD;
        const float* __restrict__ c  = ctx + b * DD;
        float acc = bt[n * DD + d];
        #pragma unroll 8
        for (int k = 0; k < DD; ++k) acc += c[k] * wc[k * DD + d];
        cp[sub][d] = acc;                   // cprojb row
        __syncthreads();
        const float* __restrict__ w1 = W1 + n * DD * DD;
        float r = b1[n * DD + d];
        #pragma unroll 8
        for (int k = 0; k < DD; ++k) r += cp[sub][k] * w1[k * DD + d];
        cpb1[bn * DD + d] = r;
        return;
    }
    const int t = blockIdx.x * 256 + threadIdx.x;
    if (t < 16384) {
        // bigp: mats 0=W2, 1=wgcf; per thread one (var,mat,c,Mi) h+l frag
        const int lane = t & 63, Mi = (t>>6)&3, c = (t>>8)&1, mat = (t>>9)&1, var = t>>10;
        const float* src = ((mat==0) ? W2 : wgcf) + (size_t)var*4096;
        const int m = 16*Mi + (lane&15), q = lane>>4;
        const int k0 = 32*c + 4*q;
        unsigned hb[8]; float lo[8];
        #pragma unroll
        for (int j = 0; j < 4; ++j) split1(src[(k0+j)*64+m],    hb[j],   lo[j]);
        #pragma unroll
        for (int j = 0; j < 4; ++j) split1(src[(k0+16+j)*64+m], hb[4+j], lo[4+j]);
        u4 hf, lf;
        hf.x = hb[0]|(hb[1]<<16); hf.y = hb[2]|(hb[3]<<16);
        hf.z = hb[4]|(hb[5]<<16); hf.w = hb[6]|(hb[7]<<16);
        lf.x = rnepk(lo[0],lo[1]); lf.y = rnepk(lo[2],lo[3]);
        lf.z = rnepk(lo[4],lo[5]); lf.w = rnepk(lo[6],lo[7]);
        u4* base = bigp + (size_t)((var*2+mat)*16)*64;
        base[((c*2+0)*4 + Mi)*64 + lane] = hf;
        base[((c*2+1)*4 + Mi)*64 + lane] = lf;
    } else if (t < 24576) {
        // wtpp / wt1p: K=16 [Wh|Wl] frags from wtpf / wt1f
        const int r = t - 16384;            // 0..8191
        const int which = r >> 12;          // 0: wtpf, 1: wt1f
        const int rr = r & 4095;
        const int lane = rr & 63, Mi = (rr>>6)&3, var = rr>>8;
        const int m = 16*Mi + (lane&15), k0 = 4*(lane>>4);
        const float* src = (which ? wt1f : wtpf) + (size_t)var*1024;
        f4 v;
        v.x = src[(k0+0)*64+m]; v.y = src[(k0+1)*64+m];
        v.z = src[(k0+2)*64+m]; v.w = src[(k0+3)*64+m];
        unsigned h0,h1,l0,l1; split4(v,h0,h1,l0,l1);
        u4 o; o.x=h0; o.y=h1; o.z=l0; o.w=l1;
        (which ? wt1p : wtpp)[(var*4+Mi)*64 + lane] = o;
    } else if (t < 25088) {
        // Ws: full-K chunks (c=0..7), h-frag + l-frag per thread
        const int r = t - 24576;
        const int lane = r & 63, c = r >> 6;
        const int n = lane & 15, q = lane >> 4;
        const int k0 = 32*c + 4*q;
        unsigned hb[8]; float lo[8];
        #pragma unroll
        for (int j = 0; j < 4; ++j) split1(Ws[(k0+j)*16+n],    hb[j],   lo[j]);
        #pragma unroll
        for (int j = 0; j < 4; ++j) split1(Ws[(k0+16+j)*16+n], hb[4+j], lo[4+j]);
        u4 hf, lf;
        hf.x = hb[0]|(hb[1]<<16); hf.y = hb[2]|(hb[3]<<16);
        hf.z = hb[4]|(hb[5]<<16); hf.w = hb[6]|(hb[7]<<16);
        lf.x = rnepk(lo[0],lo[1]); lf.y = rnepk(lo[2],lo[3]);
        lf.z = rnepk(lo[4],lo[5]); lf.w = rnepk(lo[6],lo[7]);
        wsp[(c*2+0)*64 + lane] = hf;
        wsp[(c*2+1)*64 + lane] = lf;
    }
}

// Main: block = 512 threads = 8 waves, 64 tokens; grid = 512 (R0 skeleton).
// REGISTER-CAP LEDGER: cap 128 + sel-in-LDS fits (R7/R8, VGPR 64); sel-in-regs
// spills (R6); cap<128 catastrophic (R1/R4). Never change.
// WALL LEDGER: R7 (-41us pipe work) -> -3us: latency-bound. R8 (walls 4->3,
// same work) -> -11.5us: WALLS are the lever. THIS ROUND: fold everything
// upstream of the ELU into K=16 mats off xv (exact fp32 prep): walls 3->2,
// MFMA/var 104->64, weight bytes/var 68KB->40KB.
#define PSEL_OFF 0          // 128 rows x 68 dw = 8704 dw
#define WSEL_OFF 8704       // 4 tq x 16 n x 17 = 1088 dw
#define SMEM_DW  9792       // 39168 B; 2 blocks/CU = 78KB <= 160KB

__global__ __launch_bounds__(512, 4)
void vsn_kernel(const float* __restrict__ inp,
                const u4* __restrict__ wtpp, const u4* __restrict__ wt1p,
                const u4* __restrict__ bigp, const u4* __restrict__ wsp,
                const float* __restrict__ b2, const float* __restrict__ bgc,
                const float* __restrict__ rpb, const float* __restrict__ cpb1,
                const float* __restrict__ gamma_, const float* __restrict__ beta_,
                const float* __restrict__ bs,
                float* __restrict__ out_sel, float* __restrict__ out_w) {
    __shared__ float smem[SMEM_DW];

    const int tid  = threadIdx.x;
    const int lane = tid & 63;
    const int wv   = tid >> 6;
    const int grp  = wv & 1;                    // var group (8 vars)
    const int tq   = wv >> 1;                   // token quarter (16 tokens)
    const int qd   = lane >> 4;
    const int l15  = lane & 15;
    const int tile0 = blockIdx.x * 64;
    const int b     = blockIdx.x >> 3;          // tile0 / NT
    const int tok0  = tile0 + tq * 16;

    const float* row = inp + (size_t)(tok0 + l15) * FF;   // my token's feature row

    // ---------------- logits via MFMA + softmax (per wave, 16 tokens) -------
    {
        f4 lacc = *(const f4*)(bs + 4*qd);      // n = 4*qd + reg
        #pragma unroll 4
        for (int c = 0; c < 8; ++c) {
            const u4 wh = wsp[(c*2+0)*64 + lane];
            const u4 wl = wsp[(c*2+1)*64 + lane];
            const f4 v1 = *(const f4*)(row + 32*c + 4*qd);
            const f4 v2 = *(const f4*)(row + 32*c + 16 + 4*qd);
            unsigned h0,h1,l0,l1,h2,h3,l2,l3;
            split4f(v1,h0,h1,l0,l1);
            split4f(v2,h2,h3,l2,l3);
            const bf8 Bh = mk_b4(h0,h1,h2,h3);
            const bf8 Bl = mk_b4(l0,l1,l2,l3);
            lacc = __builtin_amdgcn_mfma_f32_16x16x32_bf16(afrag(wh), Bh, lacc, 0,0,0);
            lacc = __builtin_amdgcn_mfma_f32_16x16x32_bf16(afrag(wl), Bh, lacc, 0,0,0);
            lacc = __builtin_amdgcn_mfma_f32_16x16x32_bf16(afrag(wh), Bl, lacc, 0,0,0);
        }
        float mx = fmaxf(fmaxf(lacc.x,lacc.y), fmaxf(lacc.z,lacc.w));
        mx = fmaxf(mx, __shfl_xor(mx, 16));
        mx = fmaxf(mx, __shfl_xor(mx, 32));
        float e0 = __expf(lacc.x-mx), e1 = __expf(lacc.y-mx);
        float e2 = __expf(lacc.z-mx), e3 = __expf(lacc.w-mx);
        float s = e0+e1+e2+e3;
        s += __shfl_xor(s, 16);
        s += __shfl_xor(s, 32);
        const float rs = __builtin_amdgcn_rcpf(s);
        e0 *= rs; e1 *= rs; e2 *= rs; e3 *= rs;
        const int base = WSEL_OFF + tq*272 + (4*qd)*17 + l15;
        smem[base + 0*17] = e0;
        smem[base + 1*17] = e1;
        smem[base + 2*17] = e2;
        smem[base + 3*17] = e3;
        if (grp == 0) {
            f4 o; o.x=e0; o.y=e1; o.z=e2; o.w=e3;
            *(f4*)(out_w + (size_t)(tok0 + l15)*16 + 4*qd) = o;
        }
    }

    // ---------------- per-variable GRN chain (8 vars per wave) --------------
    const int sbase = PSEL_OFF + (grp*64 + tq*16 + l15)*68 + 4*qd;

    #pragma unroll 1
    for (int vi = 0; vi < 8; ++vi) {
        const int n = grp*8 + vi;
        unsigned fh[4][2], fl[4][2];

        // wall A (K=16 pair off xv): res = wtpf^T xv + rpb ; h1pre = wt1f^T xv + cpb1
        f4 racc[4], hacc[4];
        #pragma unroll
        for (int Mi = 0; Mi < 4; ++Mi) {
            racc[Mi] = *(const f4*)(rpb  + n*DD + 16*Mi + 4*qd);
            hacc[Mi] = *(const f4*)(cpb1 + (size_t)(b*NVAR+n)*DD + 16*Mi + 4*qd);
        }
        {
            const f4 v = *(const f4*)(row + n*16 + 4*qd);
            unsigned xh0,xh1,xl0,xl1;
            split4f(v, xh0, xh1, xl0, xl1);
            const bf8 Bh = mk_bhh(xh0, xh1);
            const bf8 Bl = mk_bl0(xl0, xl1);
            #pragma unroll
            for (int Mi = 0; Mi < 4; ++Mi) {
                const u4 wA = wtpp[(n*4+Mi)*64 + lane];
                const u4 wB = wt1p[(n*4+Mi)*64 + lane];
                racc[Mi] = mfma2(racc[Mi], afrag(wA), Bh, Bl);
                hacc[Mi] = mfma2(hacc[Mi], afrag(wB), Bh, Bl);
            }
        }
        #pragma unroll
        for (int Mi = 0; Mi < 4; ++Mi) {
            f4& v = hacc[Mi];
            v.x = v.x > 0.f ? v.x : (__expf(v.x)-1.f);
            v.y = v.y > 0.f ? v.y : (__expf(v.y)-1.f);
            v.z = v.z > 0.f ? v.z : (__expf(v.z)-1.f);
            v.w = v.w > 0.f ? v.w : (__expf(v.w)-1.f);
        }
        acc_to_frags1(hacc, fh, fl);   // h1 frags

        // wall B: h2 = W2^T h1 + b2 ; g' = wgcf^T h1 + bgc  (shared h1-frags)
        f4 gacc[4];
        #pragma unroll
        for (int Mi = 0; Mi < 4; ++Mi) {
            hacc[Mi] = *(const f4*)(b2  + n*DD + 16*Mi + 4*qd);
            gacc[Mi] = *(const f4*)(bgc + n*DD + 16*Mi + 4*qd);
        }
        run_stage6_pair(bigp + (size_t)(n*2 + 0)*1024,
                        bigp + (size_t)(n*2 + 1)*1024, lane, fh, fl, hacc, gacc);

        // z = h2 * rcp(1 + exp2(-g')) + res
        f4 z[4];
        #pragma unroll
        for (int Mi = 0; Mi < 4; ++Mi) {
            const f4 gv = gacc[Mi];
            z[Mi].x = hacc[Mi].x * __builtin_amdgcn_rcpf(1.f + __builtin_amdgcn_exp2f(-gv.x)) + racc[Mi].x;
            z[Mi].y = hacc[Mi].y * __builtin_amdgcn_rcpf(1.f + __builtin_amdgcn_exp2f(-gv.y)) + racc[Mi].y;
            z[Mi].z = hacc[Mi].z * __builtin_amdgcn_rcpf(1.f + __builtin_amdgcn_exp2f(-gv.z)) + racc[Mi].z;
            z[Mi].w = hacc[Mi].w * __builtin_amdgcn_rcpf(1.f + __builtin_amdgcn_exp2f(-gv.w)) + racc[Mi].w;
        }
        // LayerNorm over d (16 in-lane + cross-quad butterfly)
        float s = 0.f;
        #pragma unroll
        for (int Mi = 0; Mi < 4; ++Mi) s += z[Mi].x + z[Mi].y + z[Mi].z + z[Mi].w;
        s += __shfl_xor(s, 16);
        s += __shfl_xor(s, 32);
        const float mu = s * (1.f/64.f);
        float q = 0.f;
        #pragma unroll
        for (int Mi = 0; Mi < 4; ++Mi) {
            float dx = z[Mi].x - mu; q += dx*dx;
            dx = z[Mi].y - mu; q += dx*dx;
            dx = z[Mi].z - mu; q += dx*dx;
            dx = z[Mi].w - mu; q += dx*dx;
        }
        q += __shfl_xor(q, 16);
        q += __shfl_xor(q, 32);
        const float rstd = rsqrtf(q*(1.f/64.f) + LN_EPS);

        const float wn = smem[WSEL_OFF + tq*272 + n*17 + l15];
        #pragma unroll
        for (int Mi = 0; Mi < 4; ++Mi) {
            const f4 gm = *(const f4*)(gamma_ + n*DD + 16*Mi + 4*qd);
            const f4 bb = *(const f4*)(beta_  + n*DD + 16*Mi + 4*qd);
            f4 cb;
            cb.x = wn*((z[Mi].x-mu)*rstd*gm.x + bb.x);
            cb.y = wn*((z[Mi].y-mu)*rstd*gm.y + bb.y);
            cb.z = wn*((z[Mi].z-mu)*rstd*gm.z + bb.z);
            cb.w = wn*((z[Mi].w-mu)*rstd*gm.w + bb.w);
            if (vi == 0) {
                *(f4*)&smem[sbase + 16*Mi] = cb;
            } else {
                const f4 o = *(f4*)&smem[sbase + 16*Mi];
                *(f4*)&smem[sbase + 16*Mi] = o + cb;
            }
        }
    }

    __syncthreads();
    {
        const int tokloc = tid >> 3;            // 0..63
        const int d0 = (tid & 7) * 8;
        const int rbase = PSEL_OFF + tokloc*68 + d0;
        const f4 a0 = *(f4*)&smem[rbase];
        const f4 a1 = *(f4*)&smem[rbase + 4];
        const f4 b0 = *(f4*)&smem[rbase + 64*68];
        const f4 b1v = *(f4*)&smem[rbase + 64*68 + 4];
        float* po = out_sel + (size_t)(tile0+tokloc)*DD + d0;
        *(f4*)po     = a0 + b0;
        *(f4*)(po+4) = a1 + b1v;
    }
}

extern "C" void kernel_launch(void* const* d_in, const int* in_sizes, int n_in,
                              void* d_out, int out_size, void* d_ws, size_t ws_size,
                              hipStream_t stream) {
    const float* inp  = (const float*)d_in[0];
    const float* ctx  = (const float*)d_in[1];
    const float* Wt   = (const float*)d_in[2];
    const float* bt   = (const float*)d_in[3];
    const float* Wctx = (const float*)d_in[4];
    const float* W1   = (const float*)d_in[5];
    const float* b1   = (const float*)d_in[6];
    const float* W2   = (const float*)d_in[7];
    const float* b2   = (const float*)d_in[8];
    const float* Wg   = (const float*)d_in[9];
    const float* bg   = (const float*)d_in[10];
    const float* Wp   = (const float*)d_in[11];
    const float* bp   = (const float*)d_in[12];
    const float* gm   = (const float*)d_in[13];
    const float* bt2  = (const float*)d_in[14];
    const float* Ws   = (const float*)d_in[15];
    const float* bs   = (const float*)d_in[16];

    float* out_sel = (float*)d_out;
    float* out_w   = out_sel + (size_t)BT * DD;

    char* ws = (char*)d_ws;
    float* cpb1 = (float*)(ws + CPB1_OFF);
    float* rpb  = (float*)(ws + RPB_OFF);
    u4* wtpp = (u4*)(ws + WTPP_OFF);
    u4* wt1p = (u4*)(ws + WT1P_OFF);
    u4* bigp = (u4*)(ws + BIGP_OFF);
    u4* wsp  = (u4*)(ws + WSP_OFF);
    float* bgc  = (float*)(ws + BGC_OFF);
    float* wgcf = (float*)(ws + WGCF_OFF);
    float* wtpf = (float*)(ws + WTPF_OFF);
    float* wt1f = (float*)(ws + WT1F_OFF);

    prep0_kernel<<<80, 256, 0, stream>>>(Wt, W1, W2, Wg, Wp, b2, bg, bt, bp,
                                         wgcf, bgc, wtpf, wt1f, rpb);
    prep_kernel<<<354, 256, 0, stream>>>(W2, wgcf, wtpf, wt1f, Ws, ctx, Wctx, bt, b1, W1,
                                         wtpp, wt1p, bigp, wsp, cpb1);
    vsn_kernel<<<BT / 64, 512, 0, stream>>>(inp, wtpp, wt1p, bigp, wsp,
                                            b2, bgc, rpb, cpb1, gm, bt2, bs,
                                            out_sel, out_w);
}